// Round 11
// baseline (1005.714 us; speedup 1.0000x reference)
//
#include <hip/hip_runtime.h>
#include <math.h>

// LLaMA-style decoder forward: B=2 S=512 D=1024 H=16 F=4096 V=32000 L=2 R=16
constexpr int B = 2, S = 512, D = 1024, H = 16, F = 4096, V = 32000, L = 2, R = 16, DH = 64;
constexpr int BS = B * S;          // 1024 rows
constexpr float LORA_SCALE = 2.0f; // alpha/r
constexpr float EPS = 1e-5f;
constexpr int RS_QKV = 3 * D;      // fused qkv row stride (ushorts)
constexpr int RS_GU  = 2 * F;      // fused g|u row stride (ushorts)

typedef __attribute__((ext_vector_type(8))) __bf16 bf16x8;
typedef __attribute__((ext_vector_type(4))) float f32x4;

__device__ __forceinline__ unsigned short f2bf(float f) {
  unsigned u = __builtin_bit_cast(unsigned, f);
  unsigned r = (u + 0x7FFFu + ((u >> 16) & 1u)) >> 16;  // RNE
  return (unsigned short)r;
}
__device__ __forceinline__ float bf2f(unsigned short us) {
  return __builtin_bit_cast(float, (unsigned)us << 16);
}
__device__ __forceinline__ void load_lds16(const void* g, void* l) {
  __builtin_amdgcn_global_load_lds((const __attribute__((address_space(1))) void*)g,
                                   (__attribute__((address_space(3))) void*)l, 16, 0, 0);
}

struct Ptr3 { const float* p[3]; };

// ---------------- RoPE cache ----------------
__global__ void rope_cache_kernel(float* __restrict__ cosb, float* __restrict__ sinb) {
  int s = blockIdx.x, j = threadIdx.x;  // j in [0,32)
  float inv = __expf(-(float)j * (9.210340371976184f / 32.0f));
  float ang = (float)s * inv;
  float c = cosf(ang), sn = sinf(ang);
  cosb[s * DH + j] = c;  cosb[s * DH + j + 32] = c;
  sinb[s * DH + j] = sn; sinb[s * DH + j + 32] = sn;
}

// ---------------- Embedding gather ----------------
__global__ void embed_kernel(const int* __restrict__ ids, const float* __restrict__ emb,
                             float* __restrict__ h) {
  int row = blockIdx.x, t = threadIdx.x;
  int id = ids[row];
  ((float4*)(h + (size_t)row * D))[t] = ((const float4*)(emb + (size_t)id * D))[t];
}

// ---------------- RMSNorm -> bf16 + fused value head (final norm only) ----------------
__global__ void rmsnorm_value_kernel(const float* __restrict__ x, const float* __restrict__ w,
                                     const float* __restrict__ vw, const float* __restrict__ vb,
                                     unsigned short* __restrict__ y, float* __restrict__ values) {
  int row = blockIdx.x, t = threadIdx.x;
  float4 xv = ((const float4*)(x + (size_t)row * D))[t];
  float ss = xv.x * xv.x + xv.y * xv.y + xv.z * xv.z + xv.w * xv.w;
  __shared__ float red[256];
  red[t] = ss; __syncthreads();
  for (int s2 = 128; s2; s2 >>= 1) { if (t < s2) red[t] += red[t + s2]; __syncthreads(); }
  float rinv = rsqrtf(red[0] * (1.0f / D) + EPS);
  float4 wv = ((const float4*)w)[t];
  float4 nx;
  nx.x = xv.x * rinv * wv.x; nx.y = xv.y * rinv * wv.y;
  nx.z = xv.z * rinv * wv.z; nx.w = xv.w * rinv * wv.w;
  ushort4 o;
  o.x = f2bf(nx.x); o.y = f2bf(nx.y); o.z = f2bf(nx.z); o.w = f2bf(nx.w);
  ((ushort4*)(y + (size_t)row * D))[t] = o;
  // fused value dot: values[row] = nx . vw + vb
  float4 vv = ((const float4*)vw)[t];
  float vd = nx.x * vv.x + nx.y * vv.y + nx.z * vv.z + nx.w * vv.w;
  __syncthreads();
  red[t] = vd; __syncthreads();
  for (int s2 = 128; s2; s2 >>= 1) { if (t < s2) red[t] += red[t + s2]; __syncthreads(); }
  if (t == 0) values[row] = red[0] + vb[0];
}

// ---------------- Fused RMSNorm + LoRA down-proj (shfl-reduce) ----------------
template <int NA>
__global__ void rms_lora_kernel(const float* __restrict__ hp, const float* __restrict__ w,
                                Ptr3 ap, unsigned short* __restrict__ xbf,
                                unsigned short* __restrict__ t2e) {
  int row = blockIdx.x, t = threadIdx.x;  // 256 threads
  int lane = t & 63;
  __shared__ float xs[D];
  __shared__ float red[256];
  float4 xv = ((const float4*)(hp + (size_t)row * D))[t];
  float ss = xv.x * xv.x + xv.y * xv.y + xv.z * xv.z + xv.w * xv.w;
  red[t] = ss; __syncthreads();
  for (int s2 = 128; s2; s2 >>= 1) { if (t < s2) red[t] += red[t + s2]; __syncthreads(); }
  float rinv = rsqrtf(red[0] * (1.0f / D) + EPS);
  float4 wv = ((const float4*)w)[t];
  float4 nx;
  nx.x = xv.x * rinv * wv.x; nx.y = xv.y * rinv * wv.y;
  nx.z = xv.z * rinv * wv.z; nx.w = xv.w * rinv * wv.w;
  xs[t * 4 + 0] = nx.x; xs[t * 4 + 1] = nx.y; xs[t * 4 + 2] = nx.z; xs[t * 4 + 3] = nx.w;
  ushort4 o;
  o.x = f2bf(nx.x); o.y = f2bf(nx.y); o.z = f2bf(nx.z); o.w = f2bf(nx.w);
  ((ushort4*)(xbf + (size_t)row * D))[t] = o;
  if (t >= NA * 16 && t < 64) t2e[(size_t)row * 64 + t] = 0;
  __syncthreads();
  int n = t & 15, g = t >> 4;
#pragma unroll
  for (int ad = 0; ad < NA; ++ad) {
    const float* a = ap.p[ad];
    float s = 0.0f;
    for (int k = g; k < D; k += 16) s = fmaf(xs[k], a[k * 16 + n], s);
    s += __shfl_xor(s, 16);
    s += __shfl_xor(s, 32);
    if (lane < 16) red[(t >> 6) * 16 + n] = s;
    __syncthreads();
    if (t < 16) t2e[(size_t)row * 64 + ad * 16 + t] =
        f2bf(LORA_SCALE * (red[t] + red[t + 16] + red[t + 32] + red[t + 48]));
    if (ad + 1 < NA) __syncthreads();
  }
}

// ---------------- LoRA down-proj from bf16 activation (o-proj) ----------------
__global__ void lora_o_kernel(const unsigned short* __restrict__ xb, const float* __restrict__ a,
                              unsigned short* __restrict__ t2e) {
  int row = blockIdx.x, t = threadIdx.x;  // 256 threads, K=D
  int lane = t & 63;
  __shared__ float xs[D];
  __shared__ float red[64];
  for (int k = t; k < D; k += 256) xs[k] = bf2f(xb[(size_t)row * D + k]);
  if (t >= 16 && t < 64) t2e[(size_t)row * 64 + t] = 0;
  __syncthreads();
  int n = t & 15, g = t >> 4;
  float s = 0.0f;
  for (int k = g; k < D; k += 16) s = fmaf(xs[k], a[k * 16 + n], s);
  s += __shfl_xor(s, 16);
  s += __shfl_xor(s, 32);
  if (lane < 16) red[(t >> 6) * 16 + n] = s;
  __syncthreads();
  if (t < 16) t2e[(size_t)row * 64 + t] =
      f2bf(LORA_SCALE * (red[t] + red[t + 16] + red[t + 32] + red[t + 48]));
}

// ---------------- Fused SwiGLU (bf16 in) + LoRA down-proj ----------------
__global__ void silu_lora_kernel(const unsigned short* __restrict__ gub, const float* __restrict__ a,
                                 unsigned short* __restrict__ gbf, unsigned short* __restrict__ t2e) {
  int row = blockIdx.x, t = threadIdx.x;  // 256 threads
  int lane = t & 63;
  __shared__ float xs[F];   // 16KB
  __shared__ float red[64];
#pragma unroll
  for (int i2 = 0; i2 < 2; ++i2) {
    int idx = i2 * 256 + t;   // 512 chunks of 8 bf16
    uint4 gv = ((const uint4*)(gub + (size_t)row * RS_GU))[idx];
    uint4 uv = ((const uint4*)(gub + (size_t)row * RS_GU + F))[idx];
    const unsigned* gw = (const unsigned*)&gv;
    const unsigned* uw = (const unsigned*)&uv;
    unsigned short go[8];
#pragma unroll
    for (int q = 0; q < 4; ++q) {
      float g0 = bf2f((unsigned short)(gw[q] & 0xffff)), g1 = bf2f((unsigned short)(gw[q] >> 16));
      float u0 = bf2f((unsigned short)(uw[q] & 0xffff)), u1 = bf2f((unsigned short)(uw[q] >> 16));
      float r0 = g0 / (1.0f + __expf(-g0)) * u0;
      float r1 = g1 / (1.0f + __expf(-g1)) * u1;
      xs[idx * 8 + q * 2] = r0; xs[idx * 8 + q * 2 + 1] = r1;
      go[q * 2] = f2bf(r0); go[q * 2 + 1] = f2bf(r1);
    }
    *(uint4*)(gbf + (size_t)row * F + idx * 8) = *(const uint4*)go;
  }
  if (t >= 16 && t < 64) t2e[(size_t)row * 64 + t] = 0;
  __syncthreads();
  int n = t & 15, g = t >> 4;
  float s = 0.0f;
  for (int k = g; k < F; k += 16) s = fmaf(xs[k], a[k * 16 + n], s);
  s += __shfl_xor(s, 16);
  s += __shfl_xor(s, 32);
  if (lane < 16) red[(t >> 6) * 16 + n] = s;
  __syncthreads();
  if (t < 16) t2e[(size_t)row * 64 + t] =
      f2bf(LORA_SCALE * (red[t] + red[t + 16] + red[t + 32] + red[t + 48]));
}

// ---------------- Merged bext builder (all layers, one dispatch) ----------------
struct BD { const float* p0; const float* p1; const float* p2;
            unsigned short* dst; int NA; int logW; int nelem; };
struct BDs { BD d[8]; };
__global__ void bext_many_kernel(BDs da) {
  int gid = blockIdx.x * 256 + threadIdx.x;
  int di = 0;
  while (gid >= da.d[di].nelem) { gid -= da.d[di].nelem; ++di; }
  const BD dd = da.d[di];
  int n = gid >> 6, kk = gid & 63;
  int W = 1 << dd.logW;
  int sel = n >> dd.logW;
  const float* bp = (sel == 0) ? dd.p0 : (sel == 1) ? dd.p1 : dd.p2;
  float v = 0.0f;
  if ((kk >> 4) == sel && sel < dd.NA)
    v = bp[(size_t)(kk & 15) * W + (n & (W - 1))];
  dd.dst[(size_t)n * 64 + kk] = f2bf(v);
}

// ---------------- Merged f32 [K,N] -> bf16 [N,K] transposes (256k x 64n tiles) ----------------
// 512B dst write segments (was 256B). Reg-staged v[16]. LDS [64n][264k] with 16B-granular
// XOR swizzle (k ^ ((n&3)<<3)) so the store phase reads contiguous uint4.
struct TD { const float* src; unsigned short* dst; int K; int N; int nblk; };
struct TDs { TD d[15]; };
__global__ __launch_bounds__(256) void transpose_many_kernel(TDs da) {
  __shared__ unsigned short tile[64 * 264];   // 33.8KB
  int bid = blockIdx.x;
  int di = 0;
  while (bid >= da.d[di].nblk) { bid -= da.d[di].nblk; ++di; }
  const TD dd = da.d[di];
  int nbx = dd.N >> 6;
  int n0 = (bid % nbx) * 64, k0 = (bid / nbx) * 256;
  int t = threadIdx.x;
  int rr = t >> 4, c4 = (t & 15) << 2;
  float4 v[16];
#pragma unroll
  for (int i = 0; i < 16; ++i)
    v[i] = *(const float4*)(dd.src + (size_t)(k0 + i * 16 + rr) * dd.N + n0 + c4);
#pragma unroll
  for (int i = 0; i < 16; ++i) {
    int k = i * 16 + rr;   // k within tile [0,256)
#pragma unroll
    for (int j = 0; j < 4; ++j) {
      int n = c4 + j;
      float e = (j == 0) ? v[i].x : (j == 1) ? v[i].y : (j == 2) ? v[i].z : v[i].w;
      tile[n * 264 + (k ^ ((n & 3) << 3))] = f2bf(e);
    }
  }
  __syncthreads();
#pragma unroll
  for (int i = 0; i < 8; ++i) {
    int flat = i * 256 + t;
    int n = flat >> 5, cw = flat & 31;         // 32 x ushort8 (16B) per n-row
    int kb = (cw * 8) ^ ((n & 3) << 3);
    *(uint4*)(dd.dst + (size_t)(n0 + n) * dd.K + k0 + cw * 8) =
        *(const uint4*)(tile + n * 264 + kb);
  }
}

// ---------------- bf16 MFMA GEMM (128-tile): depth-2 pipeline + T2 swizzle + LoRA K-ext ----------------
// OM: 0 = f32 out (opt ACC), 1 = bf16 out, 2 = bf16 out + RoPE on cols < 2*D (qkv).
template <int BN, bool ACC, bool EXT, int OM>
__global__ __launch_bounds__(256) void gemm_bf16_kernel(
    const unsigned short* __restrict__ A, const unsigned short* __restrict__ Bt,
    void* __restrict__ Cp, int M, int N, int K,
    const unsigned short* __restrict__ Ae, const unsigned short* __restrict__ Be,
    const float* __restrict__ cosb, const float* __restrict__ sinb) {
  constexpr int WM = (BN == 128) ? 2 : 4;
  constexpr int RW = 128 / WM;
  constexpr int MI = RW / 16;
  constexpr int BCH = BN / 32;
  __shared__ __align__(16) unsigned short As[2][128 * 64];
  __shared__ __align__(16) unsigned short Bs[2][BN * 64];
  int t = threadIdx.x;
  int lane = t & 63, wave = t >> 6;
  int wr = (BN == 128) ? (wave >> 1) : wave;
  int wc = (BN == 128) ? (wave & 1) : 0;
  int MT = gridDim.y, NT = gridDim.x;
  int nwg = MT * NT;
  int orig = blockIdx.y * NT + blockIdx.x;
  int qq = nwg >> 3, rr8 = nwg & 7;
  int xcd = orig & 7, pos = orig >> 3;
  int wg = (xcd < rr8) ? (xcd * (qq + 1) + pos) : (rr8 * (qq + 1) + (xcd - rr8) * qq + pos);
  int m0 = (wg % MT) * 128, n0 = (wg / MT) * BN;
  int fr = lane & 15, fq = lane >> 4;
  int xorv = fr & 7;
  f32x4 acc[MI][4] = {};
  int kIters = K / 64;
  int nIters = EXT ? kIters + 1 : kIters;

  auto STAGE = [&](int it, int buf) {
    bool ext = EXT && (it == kIters);
    int k0 = it * 64;
#pragma unroll
    for (int c = 0; c < 4; ++c) {
      int i = c * 256 + t;
      int row = i >> 3, c8 = i & 7;
      int sc = (c8 ^ (row & 7)) * 8;
      const unsigned short* src = ext ? (Ae + (size_t)(m0 + row) * 64 + sc)
                                      : (A + (size_t)(m0 + row) * K + k0 + sc);
      load_lds16(src, &As[buf][i * 8]);
    }
#pragma unroll
    for (int c = 0; c < BCH; ++c) {
      int i = c * 256 + t;
      int row = i >> 3, c8 = i & 7;
      int sc = (c8 ^ (row & 7)) * 8;
      const unsigned short* src = ext ? (Be + (size_t)(n0 + row) * 64 + sc)
                                      : (Bt + (size_t)(n0 + row) * K + k0 + sc);
      load_lds16(src, &Bs[buf][i * 8]);
    }
  };

  STAGE(0, 0);
  if (nIters > 1) STAGE(1, 1);
  int cur = 0;
  for (int it = 0; it < nIters; ++it) {
    if (it + 1 < nIters) {
      if constexpr (BN == 128) asm volatile("s_waitcnt vmcnt(8)" ::: "memory");
      else                     asm volatile("s_waitcnt vmcnt(6)" ::: "memory");
    } else {
      asm volatile("s_waitcnt vmcnt(0)" ::: "memory");
    }
    __builtin_amdgcn_s_barrier();
#pragma unroll
    for (int kk = 0; kk < 2; ++kk) {
      bf16x8 af[MI], bfr[4];
#pragma unroll
      for (int mi = 0; mi < MI; ++mi)
        af[mi] = *(const bf16x8*)(&As[cur][(wr * RW + mi * 16 + fr) * 64 + (((kk * 4 + fq) ^ xorv) << 3)]);
#pragma unroll
      for (int ni = 0; ni < 4; ++ni)
        bfr[ni] = *(const bf16x8*)(&Bs[cur][(wc * 64 + ni * 16 + fr) * 64 + (((kk * 4 + fq) ^ xorv) << 3)]);
#pragma unroll
      for (int mi = 0; mi < MI; ++mi)
#pragma unroll
        for (int ni = 0; ni < 4; ++ni)
          acc[mi][ni] = __builtin_amdgcn_mfma_f32_16x16x32_bf16(af[mi], bfr[ni], acc[mi][ni], 0, 0, 0);
    }
    __builtin_amdgcn_s_barrier();
    if (it + 2 < nIters) STAGE(it + 2, cur);
    cur ^= 1;
  }
  // epilogue (C/D layout: col=lane&15, row=(lane>>4)*4+j)
  if constexpr (OM == 0) {
    float* C = (float*)Cp;
#pragma unroll
    for (int mi = 0; mi < MI; ++mi)
#pragma unroll
      for (int ni = 0; ni < 4; ++ni)
#pragma unroll
        for (int j = 0; j < 4; ++j) {
          int r = m0 + wr * RW + mi * 16 + fq * 4 + j;
          int cl = n0 + wc * 64 + ni * 16 + fr;
          size_t idx = (size_t)r * N + cl;
          float v = acc[mi][ni][j];
          C[idx] = ACC ? C[idx] + v : v;
        }
  } else {
    unsigned short* Cb = (unsigned short*)Cp;
#pragma unroll
    for (int mi = 0; mi < MI; ++mi)
#pragma unroll
      for (int j = 0; j < 4; ++j) {
        int r = m0 + wr * RW + mi * 16 + fq * 4 + j;
        if constexpr (OM == 2) {
          int s = r & (S - 1);
#pragma unroll
          for (int ni = 0; ni < 2; ++ni) {
            int cl0 = n0 + wc * 64 + ni * 16 + fr;
            int cl1 = cl0 + 32;
            float x0 = acc[mi][ni][j], x1 = acc[mi][ni + 2][j];
            if (cl0 < 2 * D) {
              int dh = cl0 & 63;
              float cz = cosb[s * DH + dh], sz = sinb[s * DH + dh];
              float y0 = x0 * cz - x1 * sz;
              float y1 = x1 * cz + x0 * sz;
              x0 = y0; x1 = y1;
            }
            Cb[(size_t)r * N + cl0] = f2bf(x0);
            Cb[(size_t)r * N + cl1] = f2bf(x1);
          }
        } else {
#pragma unroll
          for (int ni = 0; ni < 4; ++ni) {
            int cl = n0 + wc * 64 + ni * 16 + fr;
            Cb[(size_t)r * N + cl] = f2bf(acc[mi][ni][j]);
          }
        }
      }
  }
}

// ---------------- 256x256 bf16 MFMA GEMM (lm_head) + T5 setprio ----------------
__global__ __launch_bounds__(512) void gemm256_kernel(
    const unsigned short* __restrict__ A, const unsigned short* __restrict__ Bt,
    float* __restrict__ C, int M, int N, int K) {
  __shared__ __align__(16) unsigned short As[2][256 * 64];   // 64KB
  __shared__ __align__(16) unsigned short Bs[2][256 * 64];   // 64KB
  int t = threadIdx.x;
  int lane = t & 63, wave = t >> 6;
  int wr = wave >> 2, wc = wave & 3;
  int MT = gridDim.y, NT = gridDim.x;
  int nwg = MT * NT;
  int orig = blockIdx.y * NT + blockIdx.x;
  int qq = nwg >> 3, rr8 = nwg & 7;
  int xcd = orig & 7, pos = orig >> 3;
  int wg = (xcd < rr8) ? (xcd * (qq + 1) + pos) : (rr8 * (qq + 1) + (xcd - rr8) * qq + pos);
  int m0 = (wg % MT) * 256, n0 = (wg / MT) * 256;
  int fr = lane & 15, fq = lane >> 4;
  int xorv = fr & 7;
  f32x4 acc[8][4] = {};   // 128 VGPR
  int kIters = K / 64;

  auto STAGE = [&](int it, int buf) {
    int k0 = it * 64;
#pragma unroll
    for (int c = 0; c < 4; ++c) {
      int i = c * 512 + t;
      int row = i >> 3, c8 = i & 7;
      int sc = (c8 ^ (row & 7)) * 8;
      load_lds16(A + (size_t)(m0 + row) * K + k0 + sc, &As[buf][i * 8]);
    }
#pragma unroll
    for (int c = 0; c < 4; ++c) {
      int i = c * 512 + t;
      int row = i >> 3, c8 = i & 7;
      int sc = (c8 ^ (row & 7)) * 8;
      load_lds16(Bt + (size_t)(n0 + row) * K + k0 + sc, &Bs[buf][i * 8]);
    }
  };

  STAGE(0, 0);
  if (kIters > 1) STAGE(1, 1);
  int cur = 0;
  for (int it = 0; it < kIters; ++it) {
    if (it + 1 < kIters) asm volatile("s_waitcnt vmcnt(8)" ::: "memory");
    else                 asm volatile("s_waitcnt vmcnt(0)" ::: "memory");
    __builtin_amdgcn_s_barrier();
    __builtin_amdgcn_s_setprio(1);
#pragma unroll
    for (int kk = 0; kk < 2; ++kk) {
      bf16x8 af[8], bfr[4];
#pragma unroll
      for (int mi = 0; mi < 8; ++mi)
        af[mi] = *(const bf16x8*)(&As[cur][(wr * 128 + mi * 16 + fr) * 64 + (((kk * 4 + fq) ^ xorv) << 3)]);
#pragma unroll
      for (int ni = 0; ni < 4; ++ni)
        bfr[ni] = *(const bf16x8*)(&Bs[cur][(wc * 64 + ni * 16 + fr) * 64 + (((kk * 4 + fq) ^ xorv) << 3)]);
#pragma unroll
      for (int mi = 0; mi < 8; ++mi)
#pragma unroll
        for (int ni = 0; ni < 4; ++ni)
          acc[mi][ni] = __builtin_amdgcn_mfma_f32_16x16x32_bf16(af[mi], bfr[ni], acc[mi][ni], 0, 0, 0);
    }
    __builtin_amdgcn_s_setprio(0);
    __builtin_amdgcn_s_barrier();
    if (it + 2 < kIters) STAGE(it + 2, cur);
    cur ^= 1;
  }
#pragma unroll
  for (int mi = 0; mi < 8; ++mi)
#pragma unroll
    for (int ni = 0; ni < 4; ++ni)
#pragma unroll
      for (int j = 0; j < 4; ++j) {
        int r = m0 + wr * 128 + mi * 16 + fq * 4 + j;
        int cl = n0 + wc * 64 + ni * 16 + fr;
        C[(size_t)r * N + cl] = acc[mi][ni][j];
      }
}

// ---------------- Flash attention, bf16 MFMA (4 waves, QBLK=64; paired V staging) ----------------
__global__ __launch_bounds__(256) void attn_mfma_kernel(
    const unsigned short* __restrict__ qkvb, const int* __restrict__ amask,
    unsigned short* __restrict__ o) {
  __shared__ unsigned short Qs[64 * 72];
  __shared__ unsigned short Ks[64 * 72];
  __shared__ unsigned short Vt[64 * 72];   // [dh][key]
  __shared__ unsigned short Ps[4][16 * 72];
  __shared__ float msk[64];
  int bid = blockIdx.x;
  int qt = bid & 7, hh = (bid >> 3) & (H - 1), b = bid >> 7;
  int t = threadIdx.x;
  int lane = t & 63, w = t >> 6;
  int fr = lane & 15, fq = lane >> 4;
  size_t rowbase = (size_t)b * S;
  int q0 = qt * 64;
  const float scale = 0.125f;  // 1/sqrt(64)
#pragma unroll
  for (int c = 0; c < 2; ++c) {
    int i = c * 256 + t;
    int row = i >> 3, ch = i & 7;
    *(uint4*)(Qs + row * 72 + ch * 8) =
        *(const uint4*)(qkvb + (rowbase + q0 + row) * RS_QKV + hh * DH + ch * 8);
  }
  f32x4 oacc[4] = {};
  float m_old[4] = {-1e30f, -1e30f, -1e30f, -1e30f};
  float l[4] = {};
  int qbase = q0 + w * 16;
  for (int kt = 0; kt <= qt; ++kt) {
    int kk0 = kt * 64;
#pragma unroll
    for (int c = 0; c < 2; ++c) {
      int i = c * 256 + t;
      int row = i >> 3, ch = i & 7;
      uint4 kv = *(const uint4*)(qkvb + (rowbase + kk0 + row) * RS_QKV + D + hh * DH + ch * 8);
      *(uint4*)(Ks + row * 72 + ch * 8) = kv;
    }
#pragma unroll
    for (int c = 0; c < 2; ++c) {
      int idx = c * 256 + t;
      int rp = idx >> 4, dg = idx & 15;
      const unsigned short* vsrc = qkvb + (rowbase + kk0 + rp * 2) * RS_QKV + 2 * D + hh * DH + dg * 4;
      uint2 lo = *(const uint2*)vsrc;
      uint2 hi = *(const uint2*)(vsrc + RS_QKV);
      const unsigned short* ls = (const unsigned short*)&lo;
      const unsigned short* hs = (const unsigned short*)&hi;
#pragma unroll
      for (int q = 0; q < 4; ++q) {
        unsigned pk = (unsigned)ls[q] | ((unsigned)hs[q] << 16);
        *(unsigned*)(Vt + (dg * 4 + q) * 72 + rp * 2) = pk;
      }
    }
    if (t < 64) msk[t] = (amask[b * S + kk0 + t] > 0) ? 0.0f : -1e9f;
    __syncthreads();
    bf16x8 aq[2];
    aq[0] = *(const bf16x8*)(Qs + (w * 16 + fr) * 72 + fq * 8);
    aq[1] = *(const bf16x8*)(Qs + (w * 16 + fr) * 72 + 32 + fq * 8);
    f32x4 sacc[4];
#pragma unroll
    for (int ct = 0; ct < 4; ++ct) {
      bf16x8 bk0 = *(const bf16x8*)(Ks + (ct * 16 + fr) * 72 + fq * 8);
      bf16x8 bk1 = *(const bf16x8*)(Ks + (ct * 16 + fr) * 72 + 32 + fq * 8);
      f32x4 z = {};
      z = __builtin_amdgcn_mfma_f32_16x16x32_bf16(aq[0], bk0, z, 0, 0, 0);
      sacc[ct] = __builtin_amdgcn_mfma_f32_16x16x32_bf16(aq[1], bk1, z, 0, 0, 0);
    }
    float sv[4][4];
#pragma unroll
    for (int ct = 0; ct < 4; ++ct) {
      int kg = kk0 + ct * 16 + fr;
      float mk = msk[ct * 16 + fr];
#pragma unroll
      for (int j = 0; j < 4; ++j) {
        int qg = qbase + fq * 4 + j;
        float s = sacc[ct][j] * scale + mk;
        sv[ct][j] = (kg > qg) ? -1e9f : s;
      }
    }
    float mnew[4], f[4], rsum[4];
#pragma unroll
    for (int j = 0; j < 4; ++j) {
      float mt = fmaxf(fmaxf(sv[0][j], sv[1][j]), fmaxf(sv[2][j], sv[3][j]));
      for (int off = 1; off < 16; off <<= 1) mt = fmaxf(mt, __shfl_xor(mt, off));
      mnew[j] = fmaxf(m_old[j], mt);
      f[j] = __expf(m_old[j] - mnew[j]);
      float rs = 0.0f;
#pragma unroll
      for (int ct = 0; ct < 4; ++ct) {
        float e = __expf(sv[ct][j] - mnew[j]);
        sv[ct][j] = e;
        rs += e;
      }
      for (int off = 1; off < 16; off <<= 1) rs += __shfl_xor(rs, off);
      rsum[j] = rs;
      l[j] = l[j] * f[j] + rsum[j];
      m_old[j] = mnew[j];
#pragma unroll
      for (int dt = 0; dt < 4; ++dt) oacc[dt][j] *= f[j];
    }
#pragma unroll
    for (int ct = 0; ct < 4; ++ct)
#pragma unroll
      for (int j = 0; j < 4; ++j)
        Ps[w][(fq * 4 + j) * 72 + ct * 16 + fr] = f2bf(sv[ct][j]);
    __syncthreads();
    bf16x8 pa[2];
    pa[0] = *(const bf16x8*)(&Ps[w][fr * 72 + fq * 8]);
    pa[1] = *(const bf16x8*)(&Ps[w][fr * 72 + 32 + fq * 8]);
#pragma unroll
    for (int dt = 0; dt < 4; ++dt) {
      bf16x8 vb0 = *(const bf16x8*)(Vt + (dt * 16 + fr) * 72 + fq * 8);
      bf16x8 vb1 = *(const bf16x8*)(Vt + (dt * 16 + fr) * 72 + 32 + fq * 8);
      oacc[dt] = __builtin_amdgcn_mfma_f32_16x16x32_bf16(pa[0], vb0, oacc[dt], 0, 0, 0);
      oacc[dt] = __builtin_amdgcn_mfma_f32_16x16x32_bf16(pa[1], vb1, oacc[dt], 0, 0, 0);
    }
    __syncthreads();
  }
#pragma unroll
  for (int j = 0; j < 4; ++j) {
    float rinv = 1.0f / l[j];
    int qrow = qbase + fq * 4 + j;
#pragma unroll
    for (int dt = 0; dt < 4; ++dt)
      o[(rowbase + qrow) * D + hh * DH + dt * 16 + fr] = f2bf(oacc[dt][j] * rinv);
  }
}

extern "C" void kernel_launch(void* const* d_in, const int* in_sizes, int n_in,
                              void* d_out, int out_size, void* d_ws, size_t ws_size,
                              hipStream_t stream) {
  const int*   ids     = (const int*)d_in[0];
  const int*   amask   = (const int*)d_in[1];
  const float* emb     = (const float*)d_in[2];
  const float* ln1     = (const float*)d_in[3];
  const float* ln2     = (const float*)d_in[4];
  const float* wq = (const float*)d_in[5],  *aq = (const float*)d_in[6],  *bq = (const float*)d_in[7];
  const float* wk = (const float*)d_in[8],  *ak = (const float*)d_in[9],  *bk = (const float*)d_in[10];
  const float* wv = (const float*)d_in[11], *av = (const float*)d_in[12], *bv = (const float*)d_in[13];
  const float* wo = (const float*)d_in[14], *ao = (const float*)d_in[15], *bo = (const float*)d_in[16];
  const float* wg = (const float*)d_in[17], *ag = (const float*)d_in[18], *bg = (const float*)d_in[19];
  const float* wu = (const float*)d_in[20], *au = (const float*)d_in[21], *bu = (const float*)d_in[22];
  const float* wd = (const float*)d_in[23], *ad = (const float*)d_in[24], *bd = (const float*)d_in[25];
  const float* final_ln  = (const float*)d_in[26];
  const float* lm_head_w = (const float*)d_in[27];
  const float* value_w   = (const float*)d_in[28];
  const float* value_b   = (const float*)d_in[29];

  float* out    = (float*)d_out;
  float* logits = out;
  float* values = out + (size_t)BS * V;

  // ---- workspace ----
  float* Wf = (float*)d_ws;
  float* cosb = Wf; Wf += S * DH;
  float* sinb = Wf; Wf += S * DH;
  float* h    = Wf; Wf += (size_t)BS * D;
  unsigned short* Wb = (unsigned short*)Wf;
  unsigned short* x_bf  = Wb; Wb += (size_t)BS * D;
  unsigned short* t2e   = Wb; Wb += (size_t)BS * 64;
  unsigned short* qg    = Wb; Wb += (size_t)BS * F;      // shared: qkv_bf (3D) / gbf (F)
  unsigned short* gu_bf = Wb; Wb += (size_t)BS * RS_GU;  // obf aliases its head
  unsigned short* wqkvT = Wb; Wb += (size_t)L * 3 * D * D;
  unsigned short* woT   = Wb; Wb += (size_t)L * D * D;
  unsigned short* wguT  = Wb; Wb += (size_t)L * 2 * D * F;
  unsigned short* wdT   = Wb; Wb += (size_t)L * F * D;
  unsigned short* lmT   = Wb; Wb += (size_t)D * V;
  unsigned short* beQKV = Wb; Wb += (size_t)L * 3 * D * 64;
  unsigned short* beO   = Wb; Wb += (size_t)L * D * 64;
  unsigned short* beGU  = Wb; Wb += (size_t)L * 2 * F * 64;
  unsigned short* beD   = Wb; Wb += (size_t)L * D * 64;
  unsigned short* qkv_bf = qg;                 // [BS][3D]
  unsigned short* gbf    = qg;                 // [BS][F]
  unsigned short* obf    = gu_bf;              // [BS][D]

  // ---- merged weight transposes (one dispatch, 256x64 tiles) ----
  TDs td; int tblocks = 0; int di = 0;
  auto addT = [&](const float* s, unsigned short* dp, int K_, int N_) {
    td.d[di] = {s, dp, K_, N_, (K_ / 256) * (N_ / 64)};
    tblocks += td.d[di].nblk; ++di;
  };
  for (int l = 0; l < L; ++l) {
    size_t DD = (size_t)D * D, DF = (size_t)D * F;
    addT(wq + l * DD, wqkvT + (size_t)l * 3 * DD, D, D);
    addT(wk + l * DD, wqkvT + (size_t)l * 3 * DD + DD, D, D);
    addT(wv + l * DD, wqkvT + (size_t)l * 3 * DD + 2 * DD, D, D);
    addT(wo + l * DD, woT + l * DD, D, D);
    addT(wg + l * DF, wguT + (size_t)l * 2 * DF, D, F);
    addT(wu + l * DF, wguT + (size_t)l * 2 * DF + DF, D, F);
    addT(wd + l * DF, wdT + l * DF, F, D);
  }
  addT(lm_head_w, lmT, D, V);
  transpose_many_kernel<<<dim3(tblocks), 256, 0, stream>>>(td);

  // ---- merged bext (one dispatch) ----
  BDs bd2; int belems = 0; di = 0;
  auto addB = [&](const float* p0, const float* p1, const float* p2,
                  unsigned short* dst, int NA, int logW, int N_) {
    bd2.d[di] = {p0, p1, p2, dst, NA, logW, N_ * 64};
    belems += N_ * 64; ++di;
  };
  for (int l = 0; l < L; ++l) {
    size_t oRD = (size_t)l * R * D, oRF = (size_t)l * R * F;
    addB(bq + oRD, bk + oRD, bv + oRD, beQKV + (size_t)l * 3 * D * 64, 3, 10, 3 * D);
    addB(bo + oRD, nullptr, nullptr,   beO   + (size_t)l * D * 64,     1, 10, D);
    addB(bg + oRF, bu + oRF, nullptr,  beGU  + (size_t)l * 2 * F * 64, 2, 12, 2 * F);
    addB(bd + oRD, nullptr, nullptr,   beD   + (size_t)l * D * 64,     1, 10, D);
  }
  bext_many_kernel<<<dim3(belems / 256), 256, 0, stream>>>(bd2);

  rope_cache_kernel<<<dim3(S), dim3(32), 0, stream>>>(cosb, sinb);
  embed_kernel<<<dim3(BS), dim3(256), 0, stream>>>(ids, emb, h);

  for (int l = 0; l < L; ++l) {
    size_t DD = (size_t)D * D, DF = (size_t)D * F;
    size_t oDR = (size_t)l * D * R, oFR = (size_t)l * F * R;

    // ---- attention block ----
    { Ptr3 ap = {{aq + oDR, ak + oDR, av + oDR}};
      rms_lora_kernel<3><<<dim3(BS), 256, 0, stream>>>(h, ln1 + (size_t)l * D, ap, x_bf, t2e); }
    gemm_bf16_kernel<128, false, true, 2><<<dim3(3 * D / 128, BS / 128), 256, 0, stream>>>(
        x_bf, wqkvT + (size_t)l * 3 * DD, qkv_bf, BS, 3 * D, D,
        t2e, beQKV + (size_t)l * 3 * D * 64, cosb, sinb);

    attn_mfma_kernel<<<dim3(B * H * (S / 64)), 256, 0, stream>>>(qkv_bf, amask, obf);

    lora_o_kernel<<<dim3(BS), 256, 0, stream>>>(obf, ao + oDR, t2e);
    gemm_bf16_kernel<64, true, true, 0><<<dim3(D / 64, BS / 128), 256, 0, stream>>>(
        obf, woT + l * DD, h, BS, D, D, t2e, beO + (size_t)l * D * 64, nullptr, nullptr);

    // ---- MLP block ----
    { Ptr3 ap = {{ag + oDR, au + oDR, nullptr}};
      rms_lora_kernel<2><<<dim3(BS), 256, 0, stream>>>(h, ln2 + (size_t)l * D, ap, x_bf, t2e); }
    gemm_bf16_kernel<128, false, true, 1><<<dim3(2 * F / 128, BS / 128), 256, 0, stream>>>(
        x_bf, wguT + (size_t)l * 2 * DF, gu_bf, BS, 2 * F, D,
        t2e, beGU + (size_t)l * 2 * F * 64, nullptr, nullptr);

    silu_lora_kernel<<<dim3(BS), 256, 0, stream>>>(gu_bf, ad + oFR, gbf, t2e);

    gemm_bf16_kernel<64, true, true, 0><<<dim3(D / 64, BS / 128), 256, 0, stream>>>(
        gbf, wdT + l * DF, h, BS, D, F, t2e, beD + (size_t)l * D * 64, nullptr, nullptr);
  }

  // ---- final norm + fused value head + lm head ----
  rmsnorm_value_kernel<<<dim3(BS), 256, 0, stream>>>(h, final_ln, value_w, value_b, x_bf, values);
  gemm256_kernel<<<dim3(V / 256, BS / 256), 512, 0, stream>>>(x_bf, lmT, logits, BS, V, D);
}

// Round 12
// 958.300 us; speedup vs baseline: 1.0495x; 1.0495x over previous
//
#include <hip/hip_runtime.h>
#include <math.h>

// LLaMA-style decoder forward: B=2 S=512 D=1024 H=16 F=4096 V=32000 L=2 R=16
constexpr int B = 2, S = 512, D = 1024, H = 16, F = 4096, V = 32000, L = 2, R = 16, DH = 64;
constexpr int BS = B * S;          // 1024 rows
constexpr float LORA_SCALE = 2.0f; // alpha/r
constexpr float EPS = 1e-5f;
constexpr int RS_QKV = 3 * D;      // fused qkv row stride (ushorts)
constexpr int RS_GU  = 2 * F;      // fused g|u row stride (ushorts)

typedef __attribute__((ext_vector_type(8))) __bf16 bf16x8;
typedef __attribute__((ext_vector_type(4))) float f32x4;

__device__ __forceinline__ unsigned short f2bf(float f) {
  unsigned u = __builtin_bit_cast(unsigned, f);
  unsigned r = (u + 0x7FFFu + ((u >> 16) & 1u)) >> 16;  // RNE
  return (unsigned short)r;
}
__device__ __forceinline__ float bf2f(unsigned short us) {
  return __builtin_bit_cast(float, (unsigned)us << 16);
}
__device__ __forceinline__ void load_lds16(const void* g, void* l) {
  __builtin_amdgcn_global_load_lds((const __attribute__((address_space(1))) void*)g,
                                   (__attribute__((address_space(3))) void*)l, 16, 0, 0);
}

struct Ptr3 { const float* p[3]; };

// ---------------- RoPE cache ----------------
__global__ void rope_cache_kernel(float* __restrict__ cosb, float* __restrict__ sinb) {
  int s = blockIdx.x, j = threadIdx.x;  // j in [0,32)
  float inv = __expf(-(float)j * (9.210340371976184f / 32.0f));
  float ang = (float)s * inv;
  float c = cosf(ang), sn = sinf(ang);
  cosb[s * DH + j] = c;  cosb[s * DH + j + 32] = c;
  sinb[s * DH + j] = sn; sinb[s * DH + j + 32] = sn;
}

// ---------------- Embedding gather ----------------
__global__ void embed_kernel(const int* __restrict__ ids, const float* __restrict__ emb,
                             float* __restrict__ h) {
  int row = blockIdx.x, t = threadIdx.x;
  int id = ids[row];
  ((float4*)(h + (size_t)row * D))[t] = ((const float4*)(emb + (size_t)id * D))[t];
}

// ---------------- RMSNorm -> bf16 + fused value head (final norm only) ----------------
__global__ void rmsnorm_value_kernel(const float* __restrict__ x, const float* __restrict__ w,
                                     const float* __restrict__ vw, const float* __restrict__ vb,
                                     unsigned short* __restrict__ y, float* __restrict__ values) {
  int row = blockIdx.x, t = threadIdx.x;
  float4 xv = ((const float4*)(x + (size_t)row * D))[t];
  float ss = xv.x * xv.x + xv.y * xv.y + xv.z * xv.z + xv.w * xv.w;
  __shared__ float red[256];
  red[t] = ss; __syncthreads();
  for (int s2 = 128; s2; s2 >>= 1) { if (t < s2) red[t] += red[t + s2]; __syncthreads(); }
  float rinv = rsqrtf(red[0] * (1.0f / D) + EPS);
  float4 wv = ((const float4*)w)[t];
  float4 nx;
  nx.x = xv.x * rinv * wv.x; nx.y = xv.y * rinv * wv.y;
  nx.z = xv.z * rinv * wv.z; nx.w = xv.w * rinv * wv.w;
  ushort4 o;
  o.x = f2bf(nx.x); o.y = f2bf(nx.y); o.z = f2bf(nx.z); o.w = f2bf(nx.w);
  ((ushort4*)(y + (size_t)row * D))[t] = o;
  float4 vv = ((const float4*)vw)[t];
  float vd = nx.x * vv.x + nx.y * vv.y + nx.z * vv.z + nx.w * vv.w;
  __syncthreads();
  red[t] = vd; __syncthreads();
  for (int s2 = 128; s2; s2 >>= 1) { if (t < s2) red[t] += red[t + s2]; __syncthreads(); }
  if (t == 0) values[row] = red[0] + vb[0];
}

// ---------------- Fused RMSNorm + LoRA down-proj (shfl-reduce) ----------------
template <int NA>
__global__ void rms_lora_kernel(const float* __restrict__ hp, const float* __restrict__ w,
                                Ptr3 ap, unsigned short* __restrict__ xbf,
                                unsigned short* __restrict__ t2e) {
  int row = blockIdx.x, t = threadIdx.x;  // 256 threads
  int lane = t & 63;
  __shared__ float xs[D];
  __shared__ float red[256];
  float4 xv = ((const float4*)(hp + (size_t)row * D))[t];
  float ss = xv.x * xv.x + xv.y * xv.y + xv.z * xv.z + xv.w * xv.w;
  red[t] = ss; __syncthreads();
  for (int s2 = 128; s2; s2 >>= 1) { if (t < s2) red[t] += red[t + s2]; __syncthreads(); }
  float rinv = rsqrtf(red[0] * (1.0f / D) + EPS);
  float4 wv = ((const float4*)w)[t];
  float4 nx;
  nx.x = xv.x * rinv * wv.x; nx.y = xv.y * rinv * wv.y;
  nx.z = xv.z * rinv * wv.z; nx.w = xv.w * rinv * wv.w;
  xs[t * 4 + 0] = nx.x; xs[t * 4 + 1] = nx.y; xs[t * 4 + 2] = nx.z; xs[t * 4 + 3] = nx.w;
  ushort4 o;
  o.x = f2bf(nx.x); o.y = f2bf(nx.y); o.z = f2bf(nx.z); o.w = f2bf(nx.w);
  ((ushort4*)(xbf + (size_t)row * D))[t] = o;
  if (t >= NA * 16 && t < 64) t2e[(size_t)row * 64 + t] = 0;
  __syncthreads();
  int n = t & 15, g = t >> 4;
#pragma unroll
  for (int ad = 0; ad < NA; ++ad) {
    const float* a = ap.p[ad];
    float s = 0.0f;
    for (int k = g; k < D; k += 16) s = fmaf(xs[k], a[k * 16 + n], s);
    s += __shfl_xor(s, 16);
    s += __shfl_xor(s, 32);
    if (lane < 16) red[(t >> 6) * 16 + n] = s;
    __syncthreads();
    if (t < 16) t2e[(size_t)row * 64 + ad * 16 + t] =
        f2bf(LORA_SCALE * (red[t] + red[t + 16] + red[t + 32] + red[t + 48]));
    if (ad + 1 < NA) __syncthreads();
  }
}

// ---------------- LoRA down-proj from bf16 activation (o-proj) ----------------
__global__ void lora_o_kernel(const unsigned short* __restrict__ xb, const float* __restrict__ a,
                              unsigned short* __restrict__ t2e) {
  int row = blockIdx.x, t = threadIdx.x;  // 256 threads, K=D
  int lane = t & 63;
  __shared__ float xs[D];
  __shared__ float red[64];
  for (int k = t; k < D; k += 256) xs[k] = bf2f(xb[(size_t)row * D + k]);
  if (t >= 16 && t < 64) t2e[(size_t)row * 64 + t] = 0;
  __syncthreads();
  int n = t & 15, g = t >> 4;
  float s = 0.0f;
  for (int k = g; k < D; k += 16) s = fmaf(xs[k], a[k * 16 + n], s);
  s += __shfl_xor(s, 16);
  s += __shfl_xor(s, 32);
  if (lane < 16) red[(t >> 6) * 16 + n] = s;
  __syncthreads();
  if (t < 16) t2e[(size_t)row * 64 + t] =
      f2bf(LORA_SCALE * (red[t] + red[t + 16] + red[t + 32] + red[t + 48]));
}

// ---------------- Fused SwiGLU (bf16 in) + LoRA down-proj ----------------
__global__ void silu_lora_kernel(const unsigned short* __restrict__ gub, const float* __restrict__ a,
                                 unsigned short* __restrict__ gbf, unsigned short* __restrict__ t2e) {
  int row = blockIdx.x, t = threadIdx.x;  // 256 threads
  int lane = t & 63;
  __shared__ float xs[F];   // 16KB
  __shared__ float red[64];
#pragma unroll
  for (int i2 = 0; i2 < 2; ++i2) {
    int idx = i2 * 256 + t;   // 512 chunks of 8 bf16
    uint4 gv = ((const uint4*)(gub + (size_t)row * RS_GU))[idx];
    uint4 uv = ((const uint4*)(gub + (size_t)row * RS_GU + F))[idx];
    const unsigned* gw = (const unsigned*)&gv;
    const unsigned* uw = (const unsigned*)&uv;
    unsigned short go[8];
#pragma unroll
    for (int q = 0; q < 4; ++q) {
      float g0 = bf2f((unsigned short)(gw[q] & 0xffff)), g1 = bf2f((unsigned short)(gw[q] >> 16));
      float u0 = bf2f((unsigned short)(uw[q] & 0xffff)), u1 = bf2f((unsigned short)(uw[q] >> 16));
      float r0 = g0 / (1.0f + __expf(-g0)) * u0;
      float r1 = g1 / (1.0f + __expf(-g1)) * u1;
      xs[idx * 8 + q * 2] = r0; xs[idx * 8 + q * 2 + 1] = r1;
      go[q * 2] = f2bf(r0); go[q * 2 + 1] = f2bf(r1);
    }
    *(uint4*)(gbf + (size_t)row * F + idx * 8) = *(const uint4*)go;
  }
  if (t >= 16 && t < 64) t2e[(size_t)row * 64 + t] = 0;
  __syncthreads();
  int n = t & 15, g = t >> 4;
  float s = 0.0f;
  for (int k = g; k < F; k += 16) s = fmaf(xs[k], a[k * 16 + n], s);
  s += __shfl_xor(s, 16);
  s += __shfl_xor(s, 32);
  if (lane < 16) red[(t >> 6) * 16 + n] = s;
  __syncthreads();
  if (t < 16) t2e[(size_t)row * 64 + t] =
      f2bf(LORA_SCALE * (red[t] + red[t + 16] + red[t + 32] + red[t + 48]));
}

// ---------------- Merged bext builder (all layers, one dispatch) ----------------
struct BD { const float* p0; const float* p1; const float* p2;
            unsigned short* dst; int NA; int logW; int nelem; };
struct BDs { BD d[8]; };
__global__ void bext_many_kernel(BDs da) {
  int gid = blockIdx.x * 256 + threadIdx.x;
  int di = 0;
  while (gid >= da.d[di].nelem) { gid -= da.d[di].nelem; ++di; }
  const BD dd = da.d[di];
  int n = gid >> 6, kk = gid & 63;
  int W = 1 << dd.logW;
  int sel = n >> dd.logW;
  const float* bp = (sel == 0) ? dd.p0 : (sel == 1) ? dd.p1 : dd.p2;
  float v = 0.0f;
  if ((kk >> 4) == sel && sel < dd.NA)
    v = bp[(size_t)(kk & 15) * W + (n & (W - 1))];
  dd.dst[(size_t)n * 64 + kk] = f2bf(v);
}

// ---------------- Merged f32 [K,N] -> bf16 [N,K] transposes ----------------
// 128k x 64n tile. Stage: global_load_lds LINEAR into f32 LDS (fire-and-forget, cannot be
// register-defeated), with global source chunk pre-swizzled c = c' ^ (k>>3) (rule #21).
// Read: thread (n,kc) reads 8 f32 at chunk (n>>2)^kc -> 2-way banks (free), converts, stores
// 4x256B contiguous dst rows per wave instruction.
struct TD { const float* src; unsigned short* dst; int K; int N; int nblk; };
struct TDs { TD d[15]; };
__global__ __launch_bounds__(256) void transpose_many_kernel(TDs da) {
  __shared__ __align__(16) float tile[128 * 64];   // 32KB
  int bid = blockIdx.x;
  int di = 0;
  while (bid >= da.d[di].nblk) { bid -= da.d[di].nblk; ++di; }
  const TD dd = da.d[di];
  int nbx = dd.N >> 6;
  int n0 = (bid % nbx) * 64, k0 = (bid / nbx) * 128;
  int t = threadIdx.x;
#pragma unroll
  for (int i = 0; i < 8; ++i) {
    int s = i * 256 + t;              // slot: 16B granules, lane-contiguous
    int k = s >> 4, cp = s & 15;
    int c = cp ^ (k >> 3);            // inverse-swizzled global chunk
    load_lds16(dd.src + (size_t)(k0 + k) * dd.N + n0 + c * 4, &tile[s * 4]);
  }
  asm volatile("s_waitcnt vmcnt(0)" ::: "memory");
  __builtin_amdgcn_s_barrier();
#pragma unroll
  for (int j2 = 0; j2 < 4; ++j2) {
    int flat = j2 * 256 + t;
    int n = flat >> 4, kc = flat & 15;
    int cs = ((n >> 2) ^ kc) << 2;
    unsigned short o8[8];
#pragma unroll
    for (int q = 0; q < 8; ++q) {
      int k = kc * 8 + q;
      o8[q] = f2bf(tile[k * 64 + cs + (n & 3)]);
    }
    *(uint4*)(dd.dst + (size_t)(n0 + n) * dd.K + k0 + kc * 8) = *(const uint4*)o8;
  }
}

// ---------------- bf16 MFMA GEMM: depth-2 pipeline + T2 swizzle + LoRA K-ext ----------------
// BM in {64,128}, BN in {64,128}. OM: 0 = f32 out (opt ACC), 1 = bf16 out,
// 2 = bf16 out + RoPE on cols < 2*D (qkv; requires BN=128).
template <int BM, int BN, bool ACC, bool EXT, int OM>
__global__ __launch_bounds__(256) void gemm_bf16_kernel(
    const unsigned short* __restrict__ A, const unsigned short* __restrict__ Bt,
    void* __restrict__ Cp, int M, int N, int K,
    const unsigned short* __restrict__ Ae, const unsigned short* __restrict__ Be,
    const float* __restrict__ cosb, const float* __restrict__ sinb) {
  constexpr int WC = (BM == 64 || BN == 128) ? 2 : 1;  // wave cols
  constexpr int WR = 4 / WC;                            // wave rows
  constexpr int RW = BM / WR;                           // rows per wave
  constexpr int MI = RW / 16;
  constexpr int CN = BN / WC;                           // cols per wave
  constexpr int NI = CN / 16;
  constexpr int ACH = BM / 32;
  constexpr int BCH = BN / 32;
  constexpr int NLOADS = ACH + BCH;
  __shared__ __align__(16) unsigned short As[2][BM * 64];
  __shared__ __align__(16) unsigned short Bs[2][BN * 64];
  int t = threadIdx.x;
  int lane = t & 63, wave = t >> 6;
  int wr = wave / WC, wc = wave % WC;
  int MT = gridDim.y, NT = gridDim.x;
  int nwg = MT * NT;
  int orig = blockIdx.y * NT + blockIdx.x;
  int qq = nwg >> 3, rr8 = nwg & 7;
  int xcd = orig & 7, pos = orig >> 3;
  int wg = (xcd < rr8) ? (xcd * (qq + 1) + pos) : (rr8 * (qq + 1) + (xcd - rr8) * qq + pos);
  int m0 = (wg % MT) * BM, n0 = (wg / MT) * BN;
  int fr = lane & 15, fq = lane >> 4;
  int xorv = fr & 7;
  f32x4 acc[MI][NI] = {};
  int kIters = K / 64;
  int nIters = EXT ? kIters + 1 : kIters;

  auto STAGE = [&](int it, int buf) {
    bool ext = EXT && (it == kIters);
    int k0 = it * 64;
#pragma unroll
    for (int c = 0; c < ACH; ++c) {
      int i = c * 256 + t;
      int row = i >> 3, c8 = i & 7;
      int sc = (c8 ^ (row & 7)) * 8;
      const unsigned short* src = ext ? (Ae + (size_t)(m0 + row) * 64 + sc)
                                      : (A + (size_t)(m0 + row) * K + k0 + sc);
      load_lds16(src, &As[buf][i * 8]);
    }
#pragma unroll
    for (int c = 0; c < BCH; ++c) {
      int i = c * 256 + t;
      int row = i >> 3, c8 = i & 7;
      int sc = (c8 ^ (row & 7)) * 8;
      const unsigned short* src = ext ? (Be + (size_t)(n0 + row) * 64 + sc)
                                      : (Bt + (size_t)(n0 + row) * K + k0 + sc);
      load_lds16(src, &Bs[buf][i * 8]);
    }
  };

  STAGE(0, 0);
  if (nIters > 1) STAGE(1, 1);
  int cur = 0;
  for (int it = 0; it < nIters; ++it) {
    if (it + 1 < nIters) {
      if constexpr (NLOADS == 8)      asm volatile("s_waitcnt vmcnt(8)" ::: "memory");
      else if constexpr (NLOADS == 6) asm volatile("s_waitcnt vmcnt(6)" ::: "memory");
      else                            asm volatile("s_waitcnt vmcnt(4)" ::: "memory");
    } else {
      asm volatile("s_waitcnt vmcnt(0)" ::: "memory");
    }
    __builtin_amdgcn_s_barrier();
#pragma unroll
    for (int kk = 0; kk < 2; ++kk) {
      bf16x8 af[MI], bfr[NI];
#pragma unroll
      for (int mi = 0; mi < MI; ++mi)
        af[mi] = *(const bf16x8*)(&As[cur][(wr * RW + mi * 16 + fr) * 64 + (((kk * 4 + fq) ^ xorv) << 3)]);
#pragma unroll
      for (int ni = 0; ni < NI; ++ni)
        bfr[ni] = *(const bf16x8*)(&Bs[cur][(wc * CN + ni * 16 + fr) * 64 + (((kk * 4 + fq) ^ xorv) << 3)]);
#pragma unroll
      for (int mi = 0; mi < MI; ++mi)
#pragma unroll
        for (int ni = 0; ni < NI; ++ni)
          acc[mi][ni] = __builtin_amdgcn_mfma_f32_16x16x32_bf16(af[mi], bfr[ni], acc[mi][ni], 0, 0, 0);
    }
    __builtin_amdgcn_s_barrier();
    if (it + 2 < nIters) STAGE(it + 2, cur);
    cur ^= 1;
  }
  // epilogue (C/D layout: col=lane&15, row=(lane>>4)*4+j)
  if constexpr (OM == 0) {
    float* C = (float*)Cp;
#pragma unroll
    for (int mi = 0; mi < MI; ++mi)
#pragma unroll
      for (int ni = 0; ni < NI; ++ni)
#pragma unroll
        for (int j = 0; j < 4; ++j) {
          int r = m0 + wr * RW + mi * 16 + fq * 4 + j;
          int cl = n0 + wc * CN + ni * 16 + fr;
          size_t idx = (size_t)r * N + cl;
          float v = acc[mi][ni][j];
          C[idx] = ACC ? C[idx] + v : v;
        }
  } else {
    unsigned short* Cb = (unsigned short*)Cp;
#pragma unroll
    for (int mi = 0; mi < MI; ++mi)
#pragma unroll
      for (int j = 0; j < 4; ++j) {
        int r = m0 + wr * RW + mi * 16 + fq * 4 + j;
        if constexpr (OM == 2) {
          int s = r & (S - 1);
#pragma unroll
          for (int ni = 0; ni < 2; ++ni) {
            int cl0 = n0 + wc * CN + ni * 16 + fr;
            int cl1 = cl0 + 32;
            float x0 = acc[mi][ni][j], x1 = acc[mi][ni + 2][j];
            if (cl0 < 2 * D) {
              int dh = cl0 & 63;
              float cz = cosb[s * DH + dh], sz = sinb[s * DH + dh];
              float y0 = x0 * cz - x1 * sz;
              float y1 = x1 * cz + x0 * sz;
              x0 = y0; x1 = y1;
            }
            Cb[(size_t)r * N + cl0] = f2bf(x0);
            Cb[(size_t)r * N + cl1] = f2bf(x1);
          }
        } else {
#pragma unroll
          for (int ni = 0; ni < NI; ++ni) {
            int cl = n0 + wc * CN + ni * 16 + fr;
            Cb[(size_t)r * N + cl] = f2bf(acc[mi][ni][j]);
          }
        }
      }
  }
}

// ---------------- 256x256 bf16 MFMA GEMM (lm_head) + T5 setprio ----------------
__global__ __launch_bounds__(512) void gemm256_kernel(
    const unsigned short* __restrict__ A, const unsigned short* __restrict__ Bt,
    float* __restrict__ C, int M, int N, int K) {
  __shared__ __align__(16) unsigned short As[2][256 * 64];   // 64KB
  __shared__ __align__(16) unsigned short Bs[2][256 * 64];   // 64KB
  int t = threadIdx.x;
  int lane = t & 63, wave = t >> 6;
  int wr = wave >> 2, wc = wave & 3;
  int MT = gridDim.y, NT = gridDim.x;
  int nwg = MT * NT;
  int orig = blockIdx.y * NT + blockIdx.x;
  int qq = nwg >> 3, rr8 = nwg & 7;
  int xcd = orig & 7, pos = orig >> 3;
  int wg = (xcd < rr8) ? (xcd * (qq + 1) + pos) : (rr8 * (qq + 1) + (xcd - rr8) * qq + pos);
  int m0 = (wg % MT) * 256, n0 = (wg / MT) * 256;
  int fr = lane & 15, fq = lane >> 4;
  int xorv = fr & 7;
  f32x4 acc[8][4] = {};   // 128 VGPR
  int kIters = K / 64;

  auto STAGE = [&](int it, int buf) {
    int k0 = it * 64;
#pragma unroll
    for (int c = 0; c < 4; ++c) {
      int i = c * 512 + t;
      int row = i >> 3, c8 = i & 7;
      int sc = (c8 ^ (row & 7)) * 8;
      load_lds16(A + (size_t)(m0 + row) * K + k0 + sc, &As[buf][i * 8]);
    }
#pragma unroll
    for (int c = 0; c < 4; ++c) {
      int i = c * 512 + t;
      int row = i >> 3, c8 = i & 7;
      int sc = (c8 ^ (row & 7)) * 8;
      load_lds16(Bt + (size_t)(n0 + row) * K + k0 + sc, &Bs[buf][i * 8]);
    }
  };

  STAGE(0, 0);
  if (kIters > 1) STAGE(1, 1);
  int cur = 0;
  for (int it = 0; it < kIters; ++it) {
    if (it + 1 < kIters) asm volatile("s_waitcnt vmcnt(8)" ::: "memory");
    else                 asm volatile("s_waitcnt vmcnt(0)" ::: "memory");
    __builtin_amdgcn_s_barrier();
    __builtin_amdgcn_s_setprio(1);
#pragma unroll
    for (int kk = 0; kk < 2; ++kk) {
      bf16x8 af[8], bfr[4];
#pragma unroll
      for (int mi = 0; mi < 8; ++mi)
        af[mi] = *(const bf16x8*)(&As[cur][(wr * 128 + mi * 16 + fr) * 64 + (((kk * 4 + fq) ^ xorv) << 3)]);
#pragma unroll
      for (int ni = 0; ni < 4; ++ni)
        bfr[ni] = *(const bf16x8*)(&Bs[cur][(wc * 64 + ni * 16 + fr) * 64 + (((kk * 4 + fq) ^ xorv) << 3)]);
#pragma unroll
      for (int mi = 0; mi < 8; ++mi)
#pragma unroll
        for (int ni = 0; ni < 4; ++ni)
          acc[mi][ni] = __builtin_amdgcn_mfma_f32_16x16x32_bf16(af[mi], bfr[ni], acc[mi][ni], 0, 0, 0);
    }
    __builtin_amdgcn_s_setprio(0);
    __builtin_amdgcn_s_barrier();
    if (it + 2 < kIters) STAGE(it + 2, cur);
    cur ^= 1;
  }
#pragma unroll
  for (int mi = 0; mi < 8; ++mi)
#pragma unroll
    for (int ni = 0; ni < 4; ++ni)
#pragma unroll
      for (int j = 0; j < 4; ++j) {
        int r = m0 + wr * 128 + mi * 16 + fq * 4 + j;
        int cl = n0 + wc * 64 + ni * 16 + fr;
        C[(size_t)r * N + cl] = acc[mi][ni][j];
      }
}

// ---------------- Flash attention, bf16 MFMA (4 waves, QBLK=64; paired V staging) ----------------
__global__ __launch_bounds__(256) void attn_mfma_kernel(
    const unsigned short* __restrict__ qkvb, const int* __restrict__ amask,
    unsigned short* __restrict__ o) {
  __shared__ unsigned short Qs[64 * 72];
  __shared__ unsigned short Ks[64 * 72];
  __shared__ unsigned short Vt[64 * 72];   // [dh][key]
  __shared__ unsigned short Ps[4][16 * 72];
  __shared__ float msk[64];
  int bid = blockIdx.x;
  int qt = bid & 7, hh = (bid >> 3) & (H - 1), b = bid >> 7;
  int t = threadIdx.x;
  int lane = t & 63, w = t >> 6;
  int fr = lane & 15, fq = lane >> 4;
  size_t rowbase = (size_t)b * S;
  int q0 = qt * 64;
  const float scale = 0.125f;  // 1/sqrt(64)
#pragma unroll
  for (int c = 0; c < 2; ++c) {
    int i = c * 256 + t;
    int row = i >> 3, ch = i & 7;
    *(uint4*)(Qs + row * 72 + ch * 8) =
        *(const uint4*)(qkvb + (rowbase + q0 + row) * RS_QKV + hh * DH + ch * 8);
  }
  f32x4 oacc[4] = {};
  float m_old[4] = {-1e30f, -1e30f, -1e30f, -1e30f};
  float l[4] = {};
  int qbase = q0 + w * 16;
  for (int kt = 0; kt <= qt; ++kt) {
    int kk0 = kt * 64;
#pragma unroll
    for (int c = 0; c < 2; ++c) {
      int i = c * 256 + t;
      int row = i >> 3, ch = i & 7;
      uint4 kv = *(const uint4*)(qkvb + (rowbase + kk0 + row) * RS_QKV + D + hh * DH + ch * 8);
      *(uint4*)(Ks + row * 72 + ch * 8) = kv;
    }
#pragma unroll
    for (int c = 0; c < 2; ++c) {
      int idx = c * 256 + t;
      int rp = idx >> 4, dg = idx & 15;
      const unsigned short* vsrc = qkvb + (rowbase + kk0 + rp * 2) * RS_QKV + 2 * D + hh * DH + dg * 4;
      uint2 lo = *(const uint2*)vsrc;
      uint2 hi = *(const uint2*)(vsrc + RS_QKV);
      const unsigned short* ls = (const unsigned short*)&lo;
      const unsigned short* hs = (const unsigned short*)&hi;
#pragma unroll
      for (int q = 0; q < 4; ++q) {
        unsigned pk = (unsigned)ls[q] | ((unsigned)hs[q] << 16);
        *(unsigned*)(Vt + (dg * 4 + q) * 72 + rp * 2) = pk;
      }
    }
    if (t < 64) msk[t] = (amask[b * S + kk0 + t] > 0) ? 0.0f : -1e9f;
    __syncthreads();
    bf16x8 aq[2];
    aq[0] = *(const bf16x8*)(Qs + (w * 16 + fr) * 72 + fq * 8);
    aq[1] = *(const bf16x8*)(Qs + (w * 16 + fr) * 72 + 32 + fq * 8);
    f32x4 sacc[4];
#pragma unroll
    for (int ct = 0; ct < 4; ++ct) {
      bf16x8 bk0 = *(const bf16x8*)(Ks + (ct * 16 + fr) * 72 + fq * 8);
      bf16x8 bk1 = *(const bf16x8*)(Ks + (ct * 16 + fr) * 72 + 32 + fq * 8);
      f32x4 z = {};
      z = __builtin_amdgcn_mfma_f32_16x16x32_bf16(aq[0], bk0, z, 0, 0, 0);
      sacc[ct] = __builtin_amdgcn_mfma_f32_16x16x32_bf16(aq[1], bk1, z, 0, 0, 0);
    }
    float sv[4][4];
#pragma unroll
    for (int ct = 0; ct < 4; ++ct) {
      int kg = kk0 + ct * 16 + fr;
      float mk = msk[ct * 16 + fr];
#pragma unroll
      for (int j = 0; j < 4; ++j) {
        int qg = qbase + fq * 4 + j;
        float s = sacc[ct][j] * scale + mk;
        sv[ct][j] = (kg > qg) ? -1e9f : s;
      }
    }
    float mnew[4], f[4], rsum[4];
#pragma unroll
    for (int j = 0; j < 4; ++j) {
      float mt = fmaxf(fmaxf(sv[0][j], sv[1][j]), fmaxf(sv[2][j], sv[3][j]));
      for (int off = 1; off < 16; off <<= 1) mt = fmaxf(mt, __shfl_xor(mt, off));
      mnew[j] = fmaxf(m_old[j], mt);
      f[j] = __expf(m_old[j] - mnew[j]);
      float rs = 0.0f;
#pragma unroll
      for (int ct = 0; ct < 4; ++ct) {
        float e = __expf(sv[ct][j] - mnew[j]);
        sv[ct][j] = e;
        rs += e;
      }
      for (int off = 1; off < 16; off <<= 1) rs += __shfl_xor(rs, off);
      rsum[j] = rs;
      l[j] = l[j] * f[j] + rsum[j];
      m_old[j] = mnew[j];
#pragma unroll
      for (int dt = 0; dt < 4; ++dt) oacc[dt][j] *= f[j];
    }
#pragma unroll
    for (int ct = 0; ct < 4; ++ct)
#pragma unroll
      for (int j = 0; j < 4; ++j)
        Ps[w][(fq * 4 + j) * 72 + ct * 16 + fr] = f2bf(sv[ct][j]);
    __syncthreads();
    bf16x8 pa[2];
    pa[0] = *(const bf16x8*)(&Ps[w][fr * 72 + fq * 8]);
    pa[1] = *(const bf16x8*)(&Ps[w][fr * 72 + 32 + fq * 8]);
#pragma unroll
    for (int dt = 0; dt < 4; ++dt) {
      bf16x8 vb0 = *(const bf16x8*)(Vt + (dt * 16 + fr) * 72 + fq * 8);
      bf16x8 vb1 = *(const bf16x8*)(Vt + (dt * 16 + fr) * 72 + 32 + fq * 8);
      oacc[dt] = __builtin_amdgcn_mfma_f32_16x16x32_bf16(pa[0], vb0, oacc[dt], 0, 0, 0);
      oacc[dt] = __builtin_amdgcn_mfma_f32_16x16x32_bf16(pa[1], vb1, oacc[dt], 0, 0, 0);
    }
    __syncthreads();
  }
#pragma unroll
  for (int j = 0; j < 4; ++j) {
    float rinv = 1.0f / l[j];
    int qrow = qbase + fq * 4 + j;
#pragma unroll
    for (int dt = 0; dt < 4; ++dt)
      o[(rowbase + qrow) * D + hh * DH + dt * 16 + fr] = f2bf(oacc[dt][j] * rinv);
  }
}

extern "C" void kernel_launch(void* const* d_in, const int* in_sizes, int n_in,
                              void* d_out, int out_size, void* d_ws, size_t ws_size,
                              hipStream_t stream) {
  const int*   ids     = (const int*)d_in[0];
  const int*   amask   = (const int*)d_in[1];
  const float* emb     = (const float*)d_in[2];
  const float* ln1     = (const float*)d_in[3];
  const float* ln2     = (const float*)d_in[4];
  const float* wq = (const float*)d_in[5],  *aq = (const float*)d_in[6],  *bq = (const float*)d_in[7];
  const float* wk = (const float*)d_in[8],  *ak = (const float*)d_in[9],  *bk = (const float*)d_in[10];
  const float* wv = (const float*)d_in[11], *av = (const float*)d_in[12], *bv = (const float*)d_in[13];
  const float* wo = (const float*)d_in[14], *ao = (const float*)d_in[15], *bo = (const float*)d_in[16];
  const float* wg = (const float*)d_in[17], *ag = (const float*)d_in[18], *bg = (const float*)d_in[19];
  const float* wu = (const float*)d_in[20], *au = (const float*)d_in[21], *bu = (const float*)d_in[22];
  const float* wd = (const float*)d_in[23], *ad = (const float*)d_in[24], *bd = (const float*)d_in[25];
  const float* final_ln  = (const float*)d_in[26];
  const float* lm_head_w = (const float*)d_in[27];
  const float* value_w   = (const float*)d_in[28];
  const float* value_b   = (const float*)d_in[29];

  float* out    = (float*)d_out;
  float* logits = out;
  float* values = out + (size_t)BS * V;

  // ---- workspace ----
  float* Wf = (float*)d_ws;
  float* cosb = Wf; Wf += S * DH;
  float* sinb = Wf; Wf += S * DH;
  float* h    = Wf; Wf += (size_t)BS * D;
  unsigned short* Wb = (unsigned short*)Wf;
  unsigned short* x_bf  = Wb; Wb += (size_t)BS * D;
  unsigned short* t2e   = Wb; Wb += (size_t)BS * 64;
  unsigned short* qg    = Wb; Wb += (size_t)BS * F;      // shared: qkv_bf (3D) / gbf (F)
  unsigned short* gu_bf = Wb; Wb += (size_t)BS * RS_GU;  // obf aliases its head
  unsigned short* wqkvT = Wb; Wb += (size_t)L * 3 * D * D;
  unsigned short* woT   = Wb; Wb += (size_t)L * D * D;
  unsigned short* wguT  = Wb; Wb += (size_t)L * 2 * D * F;
  unsigned short* wdT   = Wb; Wb += (size_t)L * F * D;
  unsigned short* lmT   = Wb; Wb += (size_t)D * V;
  unsigned short* beQKV = Wb; Wb += (size_t)L * 3 * D * 64;
  unsigned short* beO   = Wb; Wb += (size_t)L * D * 64;
  unsigned short* beGU  = Wb; Wb += (size_t)L * 2 * F * 64;
  unsigned short* beD   = Wb; Wb += (size_t)L * D * 64;
  unsigned short* qkv_bf = qg;                 // [BS][3D]
  unsigned short* gbf    = qg;                 // [BS][F]
  unsigned short* obf    = gu_bf;              // [BS][D]

  // ---- merged weight transposes (one dispatch, 128x64 tiles) ----
  TDs td; int tblocks = 0; int di = 0;
  auto addT = [&](const float* s, unsigned short* dp, int K_, int N_) {
    td.d[di] = {s, dp, K_, N_, (K_ / 128) * (N_ / 64)};
    tblocks += td.d[di].nblk; ++di;
  };
  for (int l = 0; l < L; ++l) {
    size_t DD = (size_t)D * D, DF = (size_t)D * F;
    addT(wq + l * DD, wqkvT + (size_t)l * 3 * DD, D, D);
    addT(wk + l * DD, wqkvT + (size_t)l * 3 * DD + DD, D, D);
    addT(wv + l * DD, wqkvT + (size_t)l * 3 * DD + 2 * DD, D, D);
    addT(wo + l * DD, woT + l * DD, D, D);
    addT(wg + l * DF, wguT + (size_t)l * 2 * DF, D, F);
    addT(wu + l * DF, wguT + (size_t)l * 2 * DF + DF, D, F);
    addT(wd + l * DF, wdT + l * DF, F, D);
  }
  addT(lm_head_w, lmT, D, V);
  transpose_many_kernel<<<dim3(tblocks), 256, 0, stream>>>(td);

  // ---- merged bext (one dispatch) ----
  BDs bd2; int belems = 0; di = 0;
  auto addB = [&](const float* p0, const float* p1, const float* p2,
                  unsigned short* dst, int NA, int logW, int N_) {
    bd2.d[di] = {p0, p1, p2, dst, NA, logW, N_ * 64};
    belems += N_ * 64; ++di;
  };
  for (int l = 0; l < L; ++l) {
    size_t oRD = (size_t)l * R * D, oRF = (size_t)l * R * F;
    addB(bq + oRD, bk + oRD, bv + oRD, beQKV + (size_t)l * 3 * D * 64, 3, 10, 3 * D);
    addB(bo + oRD, nullptr, nullptr,   beO   + (size_t)l * D * 64,     1, 10, D);
    addB(bg + oRF, bu + oRF, nullptr,  beGU  + (size_t)l * 2 * F * 64, 2, 12, 2 * F);
    addB(bd + oRD, nullptr, nullptr,   beD   + (size_t)l * D * 64,     1, 10, D);
  }
  bext_many_kernel<<<dim3(belems / 256), 256, 0, stream>>>(bd2);

  rope_cache_kernel<<<dim3(S), dim3(32), 0, stream>>>(cosb, sinb);
  embed_kernel<<<dim3(BS), dim3(256), 0, stream>>>(ids, emb, h);

  for (int l = 0; l < L; ++l) {
    size_t DD = (size_t)D * D, DF = (size_t)D * F;
    size_t oDR = (size_t)l * D * R, oFR = (size_t)l * F * R;

    // ---- attention block ----
    { Ptr3 ap = {{aq + oDR, ak + oDR, av + oDR}};
      rms_lora_kernel<3><<<dim3(BS), 256, 0, stream>>>(h, ln1 + (size_t)l * D, ap, x_bf, t2e); }
    gemm_bf16_kernel<64, 128, false, true, 2><<<dim3(3 * D / 128, BS / 64), 256, 0, stream>>>(
        x_bf, wqkvT + (size_t)l * 3 * DD, qkv_bf, BS, 3 * D, D,
        t2e, beQKV + (size_t)l * 3 * D * 64, cosb, sinb);

    attn_mfma_kernel<<<dim3(B * H * (S / 64)), 256, 0, stream>>>(qkv_bf, amask, obf);

    lora_o_kernel<<<dim3(BS), 256, 0, stream>>>(obf, ao + oDR, t2e);
    gemm_bf16_kernel<64, 64, true, true, 0><<<dim3(D / 64, BS / 64), 256, 0, stream>>>(
        obf, woT + l * DD, h, BS, D, D, t2e, beO + (size_t)l * D * 64, nullptr, nullptr);

    // ---- MLP block ----
    { Ptr3 ap = {{ag + oDR, au + oDR, nullptr}};
      rms_lora_kernel<2><<<dim3(BS), 256, 0, stream>>>(h, ln2 + (size_t)l * D, ap, x_bf, t2e); }
    gemm_bf16_kernel<128, 128, false, true, 1><<<dim3(2 * F / 128, BS / 128), 256, 0, stream>>>(
        x_bf, wguT + (size_t)l * 2 * DF, gu_bf, BS, 2 * F, D,
        t2e, beGU + (size_t)l * 2 * F * 64, nullptr, nullptr);

    silu_lora_kernel<<<dim3(BS), 256, 0, stream>>>(gu_bf, ad + oFR, gbf, t2e);

    gemm_bf16_kernel<64, 64, true, true, 0><<<dim3(D / 64, BS / 64), 256, 0, stream>>>(
        gbf, wdT + l * DF, h, BS, D, F, t2e, beD + (size_t)l * D * 64, nullptr, nullptr);
  }

  // ---- final norm + fused value head + lm head ----
  rmsnorm_value_kernel<<<dim3(BS), 256, 0, stream>>>(h, final_ln, value_w, value_b, x_bf, values);
  gemm256_kernel<<<dim3(V / 256, BS / 256), 512, 0, stream>>>(x_bf, lmT, logits, BS, V, D);
}

// Round 13
// 956.098 us; speedup vs baseline: 1.0519x; 1.0023x over previous
//
#include <hip/hip_runtime.h>
#include <math.h>

// LLaMA-style decoder forward: B=2 S=512 D=1024 H=16 F=4096 V=32000 L=2 R=16
constexpr int B = 2, S = 512, D = 1024, H = 16, F = 4096, V = 32000, L = 2, R = 16, DH = 64;
constexpr int BS = B * S;          // 1024 rows
constexpr float LORA_SCALE = 2.0f; // alpha/r
constexpr float EPS = 1e-5f;
constexpr int RS_QKV = 3 * D;      // fused qkv row stride (ushorts)
constexpr int RS_GU  = 2 * F;      // fused g|u row stride (ushorts)

typedef __attribute__((ext_vector_type(8))) __bf16 bf16x8;
typedef __attribute__((ext_vector_type(4))) float f32x4;

__device__ __forceinline__ unsigned short f2bf(float f) {
  unsigned u = __builtin_bit_cast(unsigned, f);
  unsigned r = (u + 0x7FFFu + ((u >> 16) & 1u)) >> 16;  // RNE
  return (unsigned short)r;
}
__device__ __forceinline__ float bf2f(unsigned short us) {
  return __builtin_bit_cast(float, (unsigned)us << 16);
}
__device__ __forceinline__ void load_lds16(const void* g, void* l) {
  __builtin_amdgcn_global_load_lds((const __attribute__((address_space(1))) void*)g,
                                   (__attribute__((address_space(3))) void*)l, 16, 0, 0);
}

struct Ptr3 { const float* p[3]; };

// ---------------- RoPE cache ----------------
__global__ void rope_cache_kernel(float* __restrict__ cosb, float* __restrict__ sinb) {
  int s = blockIdx.x, j = threadIdx.x;  // j in [0,32)
  float inv = __expf(-(float)j * (9.210340371976184f / 32.0f));
  float ang = (float)s * inv;
  float c = cosf(ang), sn = sinf(ang);
  cosb[s * DH + j] = c;  cosb[s * DH + j + 32] = c;
  sinb[s * DH + j] = sn; sinb[s * DH + j + 32] = sn;
}

// ---------------- Embedding gather ----------------
__global__ void embed_kernel(const int* __restrict__ ids, const float* __restrict__ emb,
                             float* __restrict__ h) {
  int row = blockIdx.x, t = threadIdx.x;
  int id = ids[row];
  ((float4*)(h + (size_t)row * D))[t] = ((const float4*)(emb + (size_t)id * D))[t];
}

// ---------------- RMSNorm -> bf16 + fused value head (final norm only) ----------------
__global__ void rmsnorm_value_kernel(const float* __restrict__ x, const float* __restrict__ w,
                                     const float* __restrict__ vw, const float* __restrict__ vb,
                                     unsigned short* __restrict__ y, float* __restrict__ values) {
  int row = blockIdx.x, t = threadIdx.x;
  int lane = t & 63;
  __shared__ float redw[4];
  __shared__ float redv[4];
  float4 xv = ((const float4*)(x + (size_t)row * D))[t];
  float ss = xv.x * xv.x + xv.y * xv.y + xv.z * xv.z + xv.w * xv.w;
#pragma unroll
  for (int off = 1; off < 64; off <<= 1) ss += __shfl_xor(ss, off);
  if (lane == 0) redw[t >> 6] = ss;
  __syncthreads();
  float rinv = rsqrtf((redw[0] + redw[1] + redw[2] + redw[3]) * (1.0f / D) + EPS);
  float4 wv = ((const float4*)w)[t];
  float4 nx;
  nx.x = xv.x * rinv * wv.x; nx.y = xv.y * rinv * wv.y;
  nx.z = xv.z * rinv * wv.z; nx.w = xv.w * rinv * wv.w;
  ushort4 o;
  o.x = f2bf(nx.x); o.y = f2bf(nx.y); o.z = f2bf(nx.z); o.w = f2bf(nx.w);
  ((ushort4*)(y + (size_t)row * D))[t] = o;
  float4 vv = ((const float4*)vw)[t];
  float vd = nx.x * vv.x + nx.y * vv.y + nx.z * vv.z + nx.w * vv.w;
#pragma unroll
  for (int off = 1; off < 64; off <<= 1) vd += __shfl_xor(vd, off);
  if (lane == 0) redv[t >> 6] = vd;
  __syncthreads();
  if (t == 0) values[row] = redv[0] + redv[1] + redv[2] + redv[3] + vb[0];
}

// ---------------- Fused RMSNorm + LoRA down-proj (shfl-reduce) ----------------
template <int NA>
__global__ void rms_lora_kernel(const float* __restrict__ hp, const float* __restrict__ w,
                                Ptr3 ap, unsigned short* __restrict__ xbf,
                                unsigned short* __restrict__ t2e) {
  int row = blockIdx.x, t = threadIdx.x;  // 256 threads
  int lane = t & 63;
  __shared__ float xs[D];
  __shared__ float red[256];
  __shared__ float redw[4];
  float4 xv = ((const float4*)(hp + (size_t)row * D))[t];
  float ss = xv.x * xv.x + xv.y * xv.y + xv.z * xv.z + xv.w * xv.w;
#pragma unroll
  for (int off = 1; off < 64; off <<= 1) ss += __shfl_xor(ss, off);
  if (lane == 0) redw[t >> 6] = ss;
  __syncthreads();
  float rinv = rsqrtf((redw[0] + redw[1] + redw[2] + redw[3]) * (1.0f / D) + EPS);
  float4 wv = ((const float4*)w)[t];
  float4 nx;
  nx.x = xv.x * rinv * wv.x; nx.y = xv.y * rinv * wv.y;
  nx.z = xv.z * rinv * wv.z; nx.w = xv.w * rinv * wv.w;
  xs[t * 4 + 0] = nx.x; xs[t * 4 + 1] = nx.y; xs[t * 4 + 2] = nx.z; xs[t * 4 + 3] = nx.w;
  ushort4 o;
  o.x = f2bf(nx.x); o.y = f2bf(nx.y); o.z = f2bf(nx.z); o.w = f2bf(nx.w);
  ((ushort4*)(xbf + (size_t)row * D))[t] = o;
  if (t >= NA * 16 && t < 64) t2e[(size_t)row * 64 + t] = 0;
  __syncthreads();
  int n = t & 15, g = t >> 4;
#pragma unroll
  for (int ad = 0; ad < NA; ++ad) {
    const float* a = ap.p[ad];
    float s = 0.0f;
    for (int k = g; k < D; k += 16) s = fmaf(xs[k], a[k * 16 + n], s);
    s += __shfl_xor(s, 16);
    s += __shfl_xor(s, 32);
    if (lane < 16) red[(t >> 6) * 16 + n] = s;
    __syncthreads();
    if (t < 16) t2e[(size_t)row * 64 + ad * 16 + t] =
        f2bf(LORA_SCALE * (red[t] + red[t + 16] + red[t + 32] + red[t + 48]));
    if (ad + 1 < NA) __syncthreads();
  }
}

// ---------------- LoRA down-proj from bf16 activation (o-proj) ----------------
__global__ void lora_o_kernel(const unsigned short* __restrict__ xb, const float* __restrict__ a,
                              unsigned short* __restrict__ t2e) {
  int row = blockIdx.x, t = threadIdx.x;  // 256 threads, K=D
  int lane = t & 63;
  __shared__ float xs[D];
  __shared__ float red[64];
  for (int k = t; k < D; k += 256) xs[k] = bf2f(xb[(size_t)row * D + k]);
  if (t >= 16 && t < 64) t2e[(size_t)row * 64 + t] = 0;
  __syncthreads();
  int n = t & 15, g = t >> 4;
  float s = 0.0f;
  for (int k = g; k < D; k += 16) s = fmaf(xs[k], a[k * 16 + n], s);
  s += __shfl_xor(s, 16);
  s += __shfl_xor(s, 32);
  if (lane < 16) red[(t >> 6) * 16 + n] = s;
  __syncthreads();
  if (t < 16) t2e[(size_t)row * 64 + t] =
      f2bf(LORA_SCALE * (red[t] + red[t + 16] + red[t + 32] + red[t + 48]));
}

// ---------------- Fused SwiGLU (bf16 in) + LoRA down-proj ----------------
__global__ void silu_lora_kernel(const unsigned short* __restrict__ gub, const float* __restrict__ a,
                                 unsigned short* __restrict__ gbf, unsigned short* __restrict__ t2e) {
  int row = blockIdx.x, t = threadIdx.x;  // 256 threads
  int lane = t & 63;
  __shared__ float xs[F];   // 16KB
  __shared__ float red[64];
#pragma unroll
  for (int i2 = 0; i2 < 2; ++i2) {
    int idx = i2 * 256 + t;   // 512 chunks of 8 bf16
    uint4 gv = ((const uint4*)(gub + (size_t)row * RS_GU))[idx];
    uint4 uv = ((const uint4*)(gub + (size_t)row * RS_GU + F))[idx];
    const unsigned* gw = (const unsigned*)&gv;
    const unsigned* uw = (const unsigned*)&uv;
    unsigned short go[8];
#pragma unroll
    for (int q = 0; q < 4; ++q) {
      float g0 = bf2f((unsigned short)(gw[q] & 0xffff)), g1 = bf2f((unsigned short)(gw[q] >> 16));
      float u0 = bf2f((unsigned short)(uw[q] & 0xffff)), u1 = bf2f((unsigned short)(uw[q] >> 16));
      float r0 = g0 / (1.0f + __expf(-g0)) * u0;
      float r1 = g1 / (1.0f + __expf(-g1)) * u1;
      xs[idx * 8 + q * 2] = r0; xs[idx * 8 + q * 2 + 1] = r1;
      go[q * 2] = f2bf(r0); go[q * 2 + 1] = f2bf(r1);
    }
    *(uint4*)(gbf + (size_t)row * F + idx * 8) = *(const uint4*)go;
  }
  if (t >= 16 && t < 64) t2e[(size_t)row * 64 + t] = 0;
  __syncthreads();
  int n = t & 15, g = t >> 4;
  float s = 0.0f;
  for (int k = g; k < F; k += 16) s = fmaf(xs[k], a[k * 16 + n], s);
  s += __shfl_xor(s, 16);
  s += __shfl_xor(s, 32);
  if (lane < 16) red[(t >> 6) * 16 + n] = s;
  __syncthreads();
  if (t < 16) t2e[(size_t)row * 64 + t] =
      f2bf(LORA_SCALE * (red[t] + red[t + 16] + red[t + 32] + red[t + 48]));
}

// ---------------- Merged bext builder (all layers, one dispatch) ----------------
struct BD { const float* p0; const float* p1; const float* p2;
            unsigned short* dst; int NA; int logW; int nelem; };
struct BDs { BD d[8]; };
__global__ void bext_many_kernel(BDs da) {
  int gid = blockIdx.x * 256 + threadIdx.x;
  int di = 0;
  while (gid >= da.d[di].nelem) { gid -= da.d[di].nelem; ++di; }
  const BD dd = da.d[di];
  int n = gid >> 6, kk = gid & 63;
  int W = 1 << dd.logW;
  int sel = n >> dd.logW;
  const float* bp = (sel == 0) ? dd.p0 : (sel == 1) ? dd.p1 : dd.p2;
  float v = 0.0f;
  if ((kk >> 4) == sel && sel < dd.NA)
    v = bp[(size_t)(kk & 15) * W + (n & (W - 1))];
  dd.dst[(size_t)n * 64 + kk] = f2bf(v);
}

// ---------------- Merged f32 [K,N] -> bf16 [N,K] transposes ----------------
// 128k x 128n tile, f32 staged via global_load_lds into 64KB LDS (fire-and-forget).
// Reads are 512B/row (was 256B) -- the read-granule experiment. Source chunk pre-swizzled
// cp ^ ((k+(k>>3))&31); read-out bank index spreads over 8 groups at 2-way (free).
struct TD { const float* src; unsigned short* dst; int K; int N; int nblk; };
struct TDs { TD d[15]; };
__global__ __launch_bounds__(256) void transpose_many_kernel(TDs da) {
  __shared__ __align__(16) float tile[128 * 128];   // 64KB
  int bid = blockIdx.x;
  int di = 0;
  while (bid >= da.d[di].nblk) { bid -= da.d[di].nblk; ++di; }
  const TD dd = da.d[di];
  int nbx = dd.N >> 7;
  int n0 = (bid % nbx) * 128, k0 = (bid / nbx) * 128;
  int t = threadIdx.x;
#pragma unroll
  for (int i = 0; i < 16; ++i) {
    int s = i * 256 + t;              // 16B slots, lane-linear dest
    int k = s >> 5, cp = s & 31;
    int swz = (k + (k >> 3)) & 31;
    load_lds16(dd.src + (size_t)(k0 + k) * dd.N + n0 + (cp ^ swz) * 4, &tile[s * 4]);
  }
  asm volatile("s_waitcnt vmcnt(0)" ::: "memory");
  __builtin_amdgcn_s_barrier();
#pragma unroll
  for (int j2 = 0; j2 < 8; ++j2) {
    int flat = j2 * 256 + t;
    int n = flat >> 4, kc = flat & 15;
    int n4 = n >> 2;
    unsigned short o8[8];
#pragma unroll
    for (int q = 0; q < 8; ++q) {
      int k = kc * 8 + q;
      int swz = (k + (k >> 3)) & 31;
      o8[q] = f2bf(tile[k * 128 + ((n4 ^ swz) << 2) + (n & 3)]);
    }
    *(uint4*)(dd.dst + (size_t)(n0 + n) * dd.K + k0 + kc * 8) = *(const uint4*)o8;
  }
}

// ---------------- bf16 MFMA GEMM: depth-2 pipeline + T2 swizzle + LoRA K-ext ----------------
// BM in {64,128}, BN in {64,128}. OM: 0 = f32 out (opt ACC), 1 = bf16 out,
// 2 = bf16 out + RoPE on cols < 2*D (qkv; requires BN=128).
template <int BM, int BN, bool ACC, bool EXT, int OM>
__global__ __launch_bounds__(256) void gemm_bf16_kernel(
    const unsigned short* __restrict__ A, const unsigned short* __restrict__ Bt,
    void* __restrict__ Cp, int M, int N, int K,
    const unsigned short* __restrict__ Ae, const unsigned short* __restrict__ Be,
    const float* __restrict__ cosb, const float* __restrict__ sinb) {
  constexpr int WC = (BM == 64 || BN == 128) ? 2 : 1;  // wave cols
  constexpr int WR = 4 / WC;                            // wave rows
  constexpr int RW = BM / WR;                           // rows per wave
  constexpr int MI = RW / 16;
  constexpr int CN = BN / WC;                           // cols per wave
  constexpr int NI = CN / 16;
  constexpr int ACH = BM / 32;
  constexpr int BCH = BN / 32;
  constexpr int NLOADS = ACH + BCH;
  __shared__ __align__(16) unsigned short As[2][BM * 64];
  __shared__ __align__(16) unsigned short Bs[2][BN * 64];
  int t = threadIdx.x;
  int lane = t & 63, wave = t >> 6;
  int wr = wave / WC, wc = wave % WC;
  int MT = gridDim.y, NT = gridDim.x;
  int nwg = MT * NT;
  int orig = blockIdx.y * NT + blockIdx.x;
  int qq = nwg >> 3, rr8 = nwg & 7;
  int xcd = orig & 7, pos = orig >> 3;
  int wg = (xcd < rr8) ? (xcd * (qq + 1) + pos) : (rr8 * (qq + 1) + (xcd - rr8) * qq + pos);
  int m0 = (wg % MT) * BM, n0 = (wg / MT) * BN;
  int fr = lane & 15, fq = lane >> 4;
  int xorv = fr & 7;
  f32x4 acc[MI][NI] = {};
  int kIters = K / 64;
  int nIters = EXT ? kIters + 1 : kIters;

  auto STAGE = [&](int it, int buf) {
    bool ext = EXT && (it == kIters);
    int k0 = it * 64;
#pragma unroll
    for (int c = 0; c < ACH; ++c) {
      int i = c * 256 + t;
      int row = i >> 3, c8 = i & 7;
      int sc = (c8 ^ (row & 7)) * 8;
      const unsigned short* src = ext ? (Ae + (size_t)(m0 + row) * 64 + sc)
                                      : (A + (size_t)(m0 + row) * K + k0 + sc);
      load_lds16(src, &As[buf][i * 8]);
    }
#pragma unroll
    for (int c = 0; c < BCH; ++c) {
      int i = c * 256 + t;
      int row = i >> 3, c8 = i & 7;
      int sc = (c8 ^ (row & 7)) * 8;
      const unsigned short* src = ext ? (Be + (size_t)(n0 + row) * 64 + sc)
                                      : (Bt + (size_t)(n0 + row) * K + k0 + sc);
      load_lds16(src, &Bs[buf][i * 8]);
    }
  };

  STAGE(0, 0);
  if (nIters > 1) STAGE(1, 1);
  int cur = 0;
  for (int it = 0; it < nIters; ++it) {
    if (it + 1 < nIters) {
      if constexpr (NLOADS == 8)      asm volatile("s_waitcnt vmcnt(8)" ::: "memory");
      else if constexpr (NLOADS == 6) asm volatile("s_waitcnt vmcnt(6)" ::: "memory");
      else                            asm volatile("s_waitcnt vmcnt(4)" ::: "memory");
    } else {
      asm volatile("s_waitcnt vmcnt(0)" ::: "memory");
    }
    __builtin_amdgcn_s_barrier();
#pragma unroll
    for (int kk = 0; kk < 2; ++kk) {
      bf16x8 af[MI], bfr[NI];
#pragma unroll
      for (int mi = 0; mi < MI; ++mi)
        af[mi] = *(const bf16x8*)(&As[cur][(wr * RW + mi * 16 + fr) * 64 + (((kk * 4 + fq) ^ xorv) << 3)]);
#pragma unroll
      for (int ni = 0; ni < NI; ++ni)
        bfr[ni] = *(const bf16x8*)(&Bs[cur][(wc * CN + ni * 16 + fr) * 64 + (((kk * 4 + fq) ^ xorv) << 3)]);
#pragma unroll
      for (int mi = 0; mi < MI; ++mi)
#pragma unroll
        for (int ni = 0; ni < NI; ++ni)
          acc[mi][ni] = __builtin_amdgcn_mfma_f32_16x16x32_bf16(af[mi], bfr[ni], acc[mi][ni], 0, 0, 0);
    }
    __builtin_amdgcn_s_barrier();
    if (it + 2 < nIters) STAGE(it + 2, cur);
    cur ^= 1;
  }
  // epilogue (C/D layout: col=lane&15, row=(lane>>4)*4+j)
  if constexpr (OM == 0) {
    float* C = (float*)Cp;
#pragma unroll
    for (int mi = 0; mi < MI; ++mi)
#pragma unroll
      for (int ni = 0; ni < NI; ++ni)
#pragma unroll
        for (int j = 0; j < 4; ++j) {
          int r = m0 + wr * RW + mi * 16 + fq * 4 + j;
          int cl = n0 + wc * CN + ni * 16 + fr;
          size_t idx = (size_t)r * N + cl;
          float v = acc[mi][ni][j];
          C[idx] = ACC ? C[idx] + v : v;
        }
  } else {
    unsigned short* Cb = (unsigned short*)Cp;
#pragma unroll
    for (int mi = 0; mi < MI; ++mi)
#pragma unroll
      for (int j = 0; j < 4; ++j) {
        int r = m0 + wr * RW + mi * 16 + fq * 4 + j;
        if constexpr (OM == 2) {
          int s = r & (S - 1);
#pragma unroll
          for (int ni = 0; ni < 2; ++ni) {
            int cl0 = n0 + wc * CN + ni * 16 + fr;
            int cl1 = cl0 + 32;
            float x0 = acc[mi][ni][j], x1 = acc[mi][ni + 2][j];
            if (cl0 < 2 * D) {
              int dh = cl0 & 63;
              float cz = cosb[s * DH + dh], sz = sinb[s * DH + dh];
              float y0 = x0 * cz - x1 * sz;
              float y1 = x1 * cz + x0 * sz;
              x0 = y0; x1 = y1;
            }
            Cb[(size_t)r * N + cl0] = f2bf(x0);
            Cb[(size_t)r * N + cl1] = f2bf(x1);
          }
        } else {
#pragma unroll
          for (int ni = 0; ni < NI; ++ni) {
            int cl = n0 + wc * CN + ni * 16 + fr;
            Cb[(size_t)r * N + cl] = f2bf(acc[mi][ni][j]);
          }
        }
      }
  }
}

// ---------------- 256x256 bf16 MFMA GEMM (lm_head) + T5 setprio ----------------
__global__ __launch_bounds__(512) void gemm256_kernel(
    const unsigned short* __restrict__ A, const unsigned short* __restrict__ Bt,
    float* __restrict__ C, int M, int N, int K) {
  __shared__ __align__(16) unsigned short As[2][256 * 64];   // 64KB
  __shared__ __align__(16) unsigned short Bs[2][256 * 64];   // 64KB
  int t = threadIdx.x;
  int lane = t & 63, wave = t >> 6;
  int wr = wave >> 2, wc = wave & 3;
  int MT = gridDim.y, NT = gridDim.x;
  int nwg = MT * NT;
  int orig = blockIdx.y * NT + blockIdx.x;
  int qq = nwg >> 3, rr8 = nwg & 7;
  int xcd = orig & 7, pos = orig >> 3;
  int wg = (xcd < rr8) ? (xcd * (qq + 1) + pos) : (rr8 * (qq + 1) + (xcd - rr8) * qq + pos);
  int m0 = (wg % MT) * 256, n0 = (wg / MT) * 256;
  int fr = lane & 15, fq = lane >> 4;
  int xorv = fr & 7;
  f32x4 acc[8][4] = {};   // 128 VGPR
  int kIters = K / 64;

  auto STAGE = [&](int it, int buf) {
    int k0 = it * 64;
#pragma unroll
    for (int c = 0; c < 4; ++c) {
      int i = c * 512 + t;
      int row = i >> 3, c8 = i & 7;
      int sc = (c8 ^ (row & 7)) * 8;
      load_lds16(A + (size_t)(m0 + row) * K + k0 + sc, &As[buf][i * 8]);
    }
#pragma unroll
    for (int c = 0; c < 4; ++c) {
      int i = c * 512 + t;
      int row = i >> 3, c8 = i & 7;
      int sc = (c8 ^ (row & 7)) * 8;
      load_lds16(Bt + (size_t)(n0 + row) * K + k0 + sc, &Bs[buf][i * 8]);
    }
  };

  STAGE(0, 0);
  if (kIters > 1) STAGE(1, 1);
  int cur = 0;
  for (int it = 0; it < kIters; ++it) {
    if (it + 1 < kIters) asm volatile("s_waitcnt vmcnt(8)" ::: "memory");
    else                 asm volatile("s_waitcnt vmcnt(0)" ::: "memory");
    __builtin_amdgcn_s_barrier();
    __builtin_amdgcn_s_setprio(1);
#pragma unroll
    for (int kk = 0; kk < 2; ++kk) {
      bf16x8 af[8], bfr[4];
#pragma unroll
      for (int mi = 0; mi < 8; ++mi)
        af[mi] = *(const bf16x8*)(&As[cur][(wr * 128 + mi * 16 + fr) * 64 + (((kk * 4 + fq) ^ xorv) << 3)]);
#pragma unroll
      for (int ni = 0; ni < 4; ++ni)
        bfr[ni] = *(const bf16x8*)(&Bs[cur][(wc * 64 + ni * 16 + fr) * 64 + (((kk * 4 + fq) ^ xorv) << 3)]);
#pragma unroll
      for (int mi = 0; mi < 8; ++mi)
#pragma unroll
        for (int ni = 0; ni < 4; ++ni)
          acc[mi][ni] = __builtin_amdgcn_mfma_f32_16x16x32_bf16(af[mi], bfr[ni], acc[mi][ni], 0, 0, 0);
    }
    __builtin_amdgcn_s_setprio(0);
    __builtin_amdgcn_s_barrier();
    if (it + 2 < kIters) STAGE(it + 2, cur);
    cur ^= 1;
  }
#pragma unroll
  for (int mi = 0; mi < 8; ++mi)
#pragma unroll
    for (int ni = 0; ni < 4; ++ni)
#pragma unroll
      for (int j = 0; j < 4; ++j) {
        int r = m0 + wr * 128 + mi * 16 + fq * 4 + j;
        int cl = n0 + wc * 64 + ni * 16 + fr;
        C[(size_t)r * N + cl] = acc[mi][ni][j];
      }
}

// ---------------- Flash attention, bf16 MFMA (4 waves, QBLK=64; paired V staging) ----------------
__global__ __launch_bounds__(256) void attn_mfma_kernel(
    const unsigned short* __restrict__ qkvb, const int* __restrict__ amask,
    unsigned short* __restrict__ o) {
  __shared__ unsigned short Qs[64 * 72];
  __shared__ unsigned short Ks[64 * 72];
  __shared__ unsigned short Vt[64 * 72];   // [dh][key]
  __shared__ unsigned short Ps[4][16 * 72];
  __shared__ float msk[64];
  int bid = blockIdx.x;
  int qt = bid & 7, hh = (bid >> 3) & (H - 1), b = bid >> 7;
  int t = threadIdx.x;
  int lane = t & 63, w = t >> 6;
  int fr = lane & 15, fq = lane >> 4;
  size_t rowbase = (size_t)b * S;
  int q0 = qt * 64;
  const float scale = 0.125f;  // 1/sqrt(64)
#pragma unroll
  for (int c = 0; c < 2; ++c) {
    int i = c * 256 + t;
    int row = i >> 3, ch = i & 7;
    *(uint4*)(Qs + row * 72 + ch * 8) =
        *(const uint4*)(qkvb + (rowbase + q0 + row) * RS_QKV + hh * DH + ch * 8);
  }
  f32x4 oacc[4] = {};
  float m_old[4] = {-1e30f, -1e30f, -1e30f, -1e30f};
  float l[4] = {};
  int qbase = q0 + w * 16;
  for (int kt = 0; kt <= qt; ++kt) {
    int kk0 = kt * 64;
#pragma unroll
    for (int c = 0; c < 2; ++c) {
      int i = c * 256 + t;
      int row = i >> 3, ch = i & 7;
      uint4 kv = *(const uint4*)(qkvb + (rowbase + kk0 + row) * RS_QKV + D + hh * DH + ch * 8);
      *(uint4*)(Ks + row * 72 + ch * 8) = kv;
    }
#pragma unroll
    for (int c = 0; c < 2; ++c) {
      int idx = c * 256 + t;
      int rp = idx >> 4, dg = idx & 15;
      const unsigned short* vsrc = qkvb + (rowbase + kk0 + rp * 2) * RS_QKV + 2 * D + hh * DH + dg * 4;
      uint2 lo = *(const uint2*)vsrc;
      uint2 hi = *(const uint2*)(vsrc + RS_QKV);
      const unsigned short* ls = (const unsigned short*)&lo;
      const unsigned short* hs = (const unsigned short*)&hi;
#pragma unroll
      for (int q = 0; q < 4; ++q) {
        unsigned pk = (unsigned)ls[q] | ((unsigned)hs[q] << 16);
        *(unsigned*)(Vt + (dg * 4 + q) * 72 + rp * 2) = pk;
      }
    }
    if (t < 64) msk[t] = (amask[b * S + kk0 + t] > 0) ? 0.0f : -1e9f;
    __syncthreads();
    bf16x8 aq[2];
    aq[0] = *(const bf16x8*)(Qs + (w * 16 + fr) * 72 + fq * 8);
    aq[1] = *(const bf16x8*)(Qs + (w * 16 + fr) * 72 + 32 + fq * 8);
    f32x4 sacc[4];
#pragma unroll
    for (int ct = 0; ct < 4; ++ct) {
      bf16x8 bk0 = *(const bf16x8*)(Ks + (ct * 16 + fr) * 72 + fq * 8);
      bf16x8 bk1 = *(const bf16x8*)(Ks + (ct * 16 + fr) * 72 + 32 + fq * 8);
      f32x4 z = {};
      z = __builtin_amdgcn_mfma_f32_16x16x32_bf16(aq[0], bk0, z, 0, 0, 0);
      sacc[ct] = __builtin_amdgcn_mfma_f32_16x16x32_bf16(aq[1], bk1, z, 0, 0, 0);
    }
    float sv[4][4];
#pragma unroll
    for (int ct = 0; ct < 4; ++ct) {
      int kg = kk0 + ct * 16 + fr;
      float mk = msk[ct * 16 + fr];
#pragma unroll
      for (int j = 0; j < 4; ++j) {
        int qg = qbase + fq * 4 + j;
        float s = sacc[ct][j] * scale + mk;
        sv[ct][j] = (kg > qg) ? -1e9f : s;
      }
    }
    float mnew[4], f[4], rsum[4];
#pragma unroll
    for (int j = 0; j < 4; ++j) {
      float mt = fmaxf(fmaxf(sv[0][j], sv[1][j]), fmaxf(sv[2][j], sv[3][j]));
      for (int off = 1; off < 16; off <<= 1) mt = fmaxf(mt, __shfl_xor(mt, off));
      mnew[j] = fmaxf(m_old[j], mt);
      f[j] = __expf(m_old[j] - mnew[j]);
      float rs = 0.0f;
#pragma unroll
      for (int ct = 0; ct < 4; ++ct) {
        float e = __expf(sv[ct][j] - mnew[j]);
        sv[ct][j] = e;
        rs += e;
      }
      for (int off = 1; off < 16; off <<= 1) rs += __shfl_xor(rs, off);
      rsum[j] = rs;
      l[j] = l[j] * f[j] + rsum[j];
      m_old[j] = mnew[j];
#pragma unroll
      for (int dt = 0; dt < 4; ++dt) oacc[dt][j] *= f[j];
    }
#pragma unroll
    for (int ct = 0; ct < 4; ++ct)
#pragma unroll
      for (int j = 0; j < 4; ++j)
        Ps[w][(fq * 4 + j) * 72 + ct * 16 + fr] = f2bf(sv[ct][j]);
    __syncthreads();
    bf16x8 pa[2];
    pa[0] = *(const bf16x8*)(&Ps[w][fr * 72 + fq * 8]);
    pa[1] = *(const bf16x8*)(&Ps[w][fr * 72 + 32 + fq * 8]);
#pragma unroll
    for (int dt = 0; dt < 4; ++dt) {
      bf16x8 vb0 = *(const bf16x8*)(Vt + (dt * 16 + fr) * 72 + fq * 8);
      bf16x8 vb1 = *(const bf16x8*)(Vt + (dt * 16 + fr) * 72 + 32 + fq * 8);
      oacc[dt] = __builtin_amdgcn_mfma_f32_16x16x32_bf16(pa[0], vb0, oacc[dt], 0, 0, 0);
      oacc[dt] = __builtin_amdgcn_mfma_f32_16x16x32_bf16(pa[1], vb1, oacc[dt], 0, 0, 0);
    }
    __syncthreads();
  }
#pragma unroll
  for (int j = 0; j < 4; ++j) {
    float rinv = 1.0f / l[j];
    int qrow = qbase + fq * 4 + j;
#pragma unroll
    for (int dt = 0; dt < 4; ++dt)
      o[(rowbase + qrow) * D + hh * DH + dt * 16 + fr] = f2bf(oacc[dt][j] * rinv);
  }
}

extern "C" void kernel_launch(void* const* d_in, const int* in_sizes, int n_in,
                              void* d_out, int out_size, void* d_ws, size_t ws_size,
                              hipStream_t stream) {
  const int*   ids     = (const int*)d_in[0];
  const int*   amask   = (const int*)d_in[1];
  const float* emb     = (const float*)d_in[2];
  const float* ln1     = (const float*)d_in[3];
  const float* ln2     = (const float*)d_in[4];
  const float* wq = (const float*)d_in[5],  *aq = (const float*)d_in[6],  *bq = (const float*)d_in[7];
  const float* wk = (const float*)d_in[8],  *ak = (const float*)d_in[9],  *bk = (const float*)d_in[10];
  const float* wv = (const float*)d_in[11], *av = (const float*)d_in[12], *bv = (const float*)d_in[13];
  const float* wo = (const float*)d_in[14], *ao = (const float*)d_in[15], *bo = (const float*)d_in[16];
  const float* wg = (const float*)d_in[17], *ag = (const float*)d_in[18], *bg = (const float*)d_in[19];
  const float* wu = (const float*)d_in[20], *au = (const float*)d_in[21], *bu = (const float*)d_in[22];
  const float* wd = (const float*)d_in[23], *ad = (const float*)d_in[24], *bd = (const float*)d_in[25];
  const float* final_ln  = (const float*)d_in[26];
  const float* lm_head_w = (const float*)d_in[27];
  const float* value_w   = (const float*)d_in[28];
  const float* value_b   = (const float*)d_in[29];

  float* out    = (float*)d_out;
  float* logits = out;
  float* values = out + (size_t)BS * V;

  // ---- workspace ----
  float* Wf = (float*)d_ws;
  float* cosb = Wf; Wf += S * DH;
  float* sinb = Wf; Wf += S * DH;
  float* h    = Wf; Wf += (size_t)BS * D;
  unsigned short* Wb = (unsigned short*)Wf;
  unsigned short* x_bf  = Wb; Wb += (size_t)BS * D;
  unsigned short* t2e   = Wb; Wb += (size_t)BS * 64;
  unsigned short* qg    = Wb; Wb += (size_t)BS * F;      // shared: qkv_bf (3D) / gbf (F)
  unsigned short* gu_bf = Wb; Wb += (size_t)BS * RS_GU;  // obf aliases its head
  unsigned short* wqkvT = Wb; Wb += (size_t)L * 3 * D * D;
  unsigned short* woT   = Wb; Wb += (size_t)L * D * D;
  unsigned short* wguT  = Wb; Wb += (size_t)L * 2 * D * F;
  unsigned short* wdT   = Wb; Wb += (size_t)L * F * D;
  unsigned short* lmT   = Wb; Wb += (size_t)D * V;
  unsigned short* beQKV = Wb; Wb += (size_t)L * 3 * D * 64;
  unsigned short* beO   = Wb; Wb += (size_t)L * D * 64;
  unsigned short* beGU  = Wb; Wb += (size_t)L * 2 * F * 64;
  unsigned short* beD   = Wb; Wb += (size_t)L * D * 64;
  unsigned short* qkv_bf = qg;                 // [BS][3D]
  unsigned short* gbf    = qg;                 // [BS][F]
  unsigned short* obf    = gu_bf;              // [BS][D]

  // ---- merged weight transposes (one dispatch, 128x128 tiles) ----
  TDs td; int tblocks = 0; int di = 0;
  auto addT = [&](const float* s, unsigned short* dp, int K_, int N_) {
    td.d[di] = {s, dp, K_, N_, (K_ / 128) * (N_ / 128)};
    tblocks += td.d[di].nblk; ++di;
  };
  for (int l = 0; l < L; ++l) {
    size_t DD = (size_t)D * D, DF = (size_t)D * F;
    addT(wq + l * DD, wqkvT + (size_t)l * 3 * DD, D, D);
    addT(wk + l * DD, wqkvT + (size_t)l * 3 * DD + DD, D, D);
    addT(wv + l * DD, wqkvT + (size_t)l * 3 * DD + 2 * DD, D, D);
    addT(wo + l * DD, woT + l * DD, D, D);
    addT(wg + l * DF, wguT + (size_t)l * 2 * DF, D, F);
    addT(wu + l * DF, wguT + (size_t)l * 2 * DF + DF, D, F);
    addT(wd + l * DF, wdT + l * DF, F, D);
  }
  addT(lm_head_w, lmT, D, V);
  transpose_many_kernel<<<dim3(tblocks), 256, 0, stream>>>(td);

  // ---- merged bext (one dispatch) ----
  BDs bd2; int belems = 0; di = 0;
  auto addB = [&](const float* p0, const float* p1, const float* p2,
                  unsigned short* dst, int NA, int logW, int N_) {
    bd2.d[di] = {p0, p1, p2, dst, NA, logW, N_ * 64};
    belems += N_ * 64; ++di;
  };
  for (int l = 0; l < L; ++l) {
    size_t oRD = (size_t)l * R * D, oRF = (size_t)l * R * F;
    addB(bq + oRD, bk + oRD, bv + oRD, beQKV + (size_t)l * 3 * D * 64, 3, 10, 3 * D);
    addB(bo + oRD, nullptr, nullptr,   beO   + (size_t)l * D * 64,     1, 10, D);
    addB(bg + oRF, bu + oRF, nullptr,  beGU  + (size_t)l * 2 * F * 64, 2, 12, 2 * F);
    addB(bd + oRD, nullptr, nullptr,   beD   + (size_t)l * D * 64,     1, 10, D);
  }
  bext_many_kernel<<<dim3(belems / 256), 256, 0, stream>>>(bd2);

  rope_cache_kernel<<<dim3(S), dim3(32), 0, stream>>>(cosb, sinb);
  embed_kernel<<<dim3(BS), dim3(256), 0, stream>>>(ids, emb, h);

  for (int l = 0; l < L; ++l) {
    size_t DD = (size_t)D * D, DF = (size_t)D * F;
    size_t oDR = (size_t)l * D * R, oFR = (size_t)l * F * R;

    // ---- attention block ----
    { Ptr3 ap = {{aq + oDR, ak + oDR, av + oDR}};
      rms_lora_kernel<3><<<dim3(BS), 256, 0, stream>>>(h, ln1 + (size_t)l * D, ap, x_bf, t2e); }
    gemm_bf16_kernel<64, 128, false, true, 2><<<dim3(3 * D / 128, BS / 64), 256, 0, stream>>>(
        x_bf, wqkvT + (size_t)l * 3 * DD, qkv_bf, BS, 3 * D, D,
        t2e, beQKV + (size_t)l * 3 * D * 64, cosb, sinb);

    attn_mfma_kernel<<<dim3(B * H * (S / 64)), 256, 0, stream>>>(qkv_bf, amask, obf);

    lora_o_kernel<<<dim3(BS), 256, 0, stream>>>(obf, ao + oDR, t2e);
    gemm_bf16_kernel<64, 64, true, true, 0><<<dim3(D / 64, BS / 64), 256, 0, stream>>>(
        obf, woT + l * DD, h, BS, D, D, t2e, beO + (size_t)l * D * 64, nullptr, nullptr);

    // ---- MLP block ----
    { Ptr3 ap = {{ag + oDR, au + oDR, nullptr}};
      rms_lora_kernel<2><<<dim3(BS), 256, 0, stream>>>(h, ln2 + (size_t)l * D, ap, x_bf, t2e); }
    gemm_bf16_kernel<128, 128, false, true, 1><<<dim3(2 * F / 128, BS / 128), 256, 0, stream>>>(
        x_bf, wguT + (size_t)l * 2 * DF, gu_bf, BS, 2 * F, D,
        t2e, beGU + (size_t)l * 2 * F * 64, nullptr, nullptr);

    silu_lora_kernel<<<dim3(BS), 256, 0, stream>>>(gu_bf, ad + oFR, gbf, t2e);

    gemm_bf16_kernel<64, 64, true, true, 0><<<dim3(D / 64, BS / 64), 256, 0, stream>>>(
        gbf, wdT + l * DF, h, BS, D, F, t2e, beD + (size_t)l * D * 64, nullptr, nullptr);
  }

  // ---- final norm + fused value head + lm head ----
  rmsnorm_value_kernel<<<dim3(BS), 256, 0, stream>>>(h, final_ln, value_w, value_b, x_bf, values);
  gemm256_kernel<<<dim3(V / 256, BS / 256), 512, 0, stream>>>(x_bf, lmT, logits, BS, V, D);
}

// Round 14
// 911.412 us; speedup vs baseline: 1.1035x; 1.0490x over previous
//
#include <hip/hip_runtime.h>
#include <math.h>

// LLaMA-style decoder forward: B=2 S=512 D=1024 H=16 F=4096 V=32000 L=2 R=16
constexpr int B = 2, S = 512, D = 1024, H = 16, F = 4096, V = 32000, L = 2, R = 16, DH = 64;
constexpr int BS = B * S;          // 1024 rows
constexpr float LORA_SCALE = 2.0f; // alpha/r
constexpr float EPS = 1e-5f;
constexpr int RS_QKV = 3 * D;      // fused qkv row stride (ushorts)
constexpr int RS_GU  = 2 * F;      // fused g|u row stride (ushorts)

typedef __attribute__((ext_vector_type(8))) __bf16 bf16x8;
typedef __attribute__((ext_vector_type(4))) float f32x4;

__device__ __forceinline__ unsigned short f2bf(float f) {
  unsigned u = __builtin_bit_cast(unsigned, f);
  unsigned r = (u + 0x7FFFu + ((u >> 16) & 1u)) >> 16;  // RNE
  return (unsigned short)r;
}
__device__ __forceinline__ float bf2f(unsigned short us) {
  return __builtin_bit_cast(float, (unsigned)us << 16);
}
__device__ __forceinline__ void load_lds16(const void* g, void* l) {
  __builtin_amdgcn_global_load_lds((const __attribute__((address_space(1))) void*)g,
                                   (__attribute__((address_space(3))) void*)l, 16, 0, 0);
}

struct Ptr3 { const float* p[3]; };

// ---------------- RoPE cache ----------------
__global__ void rope_cache_kernel(float* __restrict__ cosb, float* __restrict__ sinb) {
  int s = blockIdx.x, j = threadIdx.x;  // j in [0,32)
  float inv = __expf(-(float)j * (9.210340371976184f / 32.0f));
  float ang = (float)s * inv;
  float c = cosf(ang), sn = sinf(ang);
  cosb[s * DH + j] = c;  cosb[s * DH + j + 32] = c;
  sinb[s * DH + j] = sn; sinb[s * DH + j + 32] = sn;
}

// ---------------- Embedding gather ----------------
__global__ void embed_kernel(const int* __restrict__ ids, const float* __restrict__ emb,
                             float* __restrict__ h) {
  int row = blockIdx.x, t = threadIdx.x;
  int id = ids[row];
  ((float4*)(h + (size_t)row * D))[t] = ((const float4*)(emb + (size_t)id * D))[t];
}

// ---------------- RMSNorm -> bf16 + fused value head (final norm only) ----------------
__global__ void rmsnorm_value_kernel(const float* __restrict__ x, const float* __restrict__ w,
                                     const float* __restrict__ vw, const float* __restrict__ vb,
                                     unsigned short* __restrict__ y, float* __restrict__ values) {
  int row = blockIdx.x, t = threadIdx.x;
  int lane = t & 63;
  __shared__ float redw[4];
  __shared__ float redv[4];
  float4 xv = ((const float4*)(x + (size_t)row * D))[t];
  float ss = xv.x * xv.x + xv.y * xv.y + xv.z * xv.z + xv.w * xv.w;
#pragma unroll
  for (int off = 1; off < 64; off <<= 1) ss += __shfl_xor(ss, off);
  if (lane == 0) redw[t >> 6] = ss;
  __syncthreads();
  float rinv = rsqrtf((redw[0] + redw[1] + redw[2] + redw[3]) * (1.0f / D) + EPS);
  float4 wv = ((const float4*)w)[t];
  float4 nx;
  nx.x = xv.x * rinv * wv.x; nx.y = xv.y * rinv * wv.y;
  nx.z = xv.z * rinv * wv.z; nx.w = xv.w * rinv * wv.w;
  ushort4 o;
  o.x = f2bf(nx.x); o.y = f2bf(nx.y); o.z = f2bf(nx.z); o.w = f2bf(nx.w);
  ((ushort4*)(y + (size_t)row * D))[t] = o;
  float4 vv = ((const float4*)vw)[t];
  float vd = nx.x * vv.x + nx.y * vv.y + nx.z * vv.z + nx.w * vv.w;
#pragma unroll
  for (int off = 1; off < 64; off <<= 1) vd += __shfl_xor(vd, off);
  if (lane == 0) redv[t >> 6] = vd;
  __syncthreads();
  if (t == 0) values[row] = redv[0] + redv[1] + redv[2] + redv[3] + vb[0];
}

// ---------------- Fused RMSNorm + LoRA down-proj (shfl-reduce) ----------------
template <int NA>
__global__ void rms_lora_kernel(const float* __restrict__ hp, const float* __restrict__ w,
                                Ptr3 ap, unsigned short* __restrict__ xbf,
                                unsigned short* __restrict__ t2e) {
  int row = blockIdx.x, t = threadIdx.x;  // 256 threads
  int lane = t & 63;
  __shared__ float xs[D];
  __shared__ float red[256];
  __shared__ float redw[4];
  float4 xv = ((const float4*)(hp + (size_t)row * D))[t];
  float ss = xv.x * xv.x + xv.y * xv.y + xv.z * xv.z + xv.w * xv.w;
#pragma unroll
  for (int off = 1; off < 64; off <<= 1) ss += __shfl_xor(ss, off);
  if (lane == 0) redw[t >> 6] = ss;
  __syncthreads();
  float rinv = rsqrtf((redw[0] + redw[1] + redw[2] + redw[3]) * (1.0f / D) + EPS);
  float4 wv = ((const float4*)w)[t];
  float4 nx;
  nx.x = xv.x * rinv * wv.x; nx.y = xv.y * rinv * wv.y;
  nx.z = xv.z * rinv * wv.z; nx.w = xv.w * rinv * wv.w;
  xs[t * 4 + 0] = nx.x; xs[t * 4 + 1] = nx.y; xs[t * 4 + 2] = nx.z; xs[t * 4 + 3] = nx.w;
  ushort4 o;
  o.x = f2bf(nx.x); o.y = f2bf(nx.y); o.z = f2bf(nx.z); o.w = f2bf(nx.w);
  ((ushort4*)(xbf + (size_t)row * D))[t] = o;
  if (t >= NA * 16 && t < 64) t2e[(size_t)row * 64 + t] = 0;
  __syncthreads();
  int n = t & 15, g = t >> 4;
#pragma unroll
  for (int ad = 0; ad < NA; ++ad) {
    const float* a = ap.p[ad];
    float s = 0.0f;
    for (int k = g; k < D; k += 16) s = fmaf(xs[k], a[k * 16 + n], s);
    s += __shfl_xor(s, 16);
    s += __shfl_xor(s, 32);
    if (lane < 16) red[(t >> 6) * 16 + n] = s;
    __syncthreads();
    if (t < 16) t2e[(size_t)row * 64 + ad * 16 + t] =
        f2bf(LORA_SCALE * (red[t] + red[t + 16] + red[t + 32] + red[t + 48]));
    if (ad + 1 < NA) __syncthreads();
  }
}

// ---------------- LoRA down-proj from bf16 activation (o-proj) ----------------
__global__ void lora_o_kernel(const unsigned short* __restrict__ xb, const float* __restrict__ a,
                              unsigned short* __restrict__ t2e) {
  int row = blockIdx.x, t = threadIdx.x;  // 256 threads, K=D
  int lane = t & 63;
  __shared__ float xs[D];
  __shared__ float red[64];
  for (int k = t; k < D; k += 256) xs[k] = bf2f(xb[(size_t)row * D + k]);
  if (t >= 16 && t < 64) t2e[(size_t)row * 64 + t] = 0;
  __syncthreads();
  int n = t & 15, g = t >> 4;
  float s = 0.0f;
  for (int k = g; k < D; k += 16) s = fmaf(xs[k], a[k * 16 + n], s);
  s += __shfl_xor(s, 16);
  s += __shfl_xor(s, 32);
  if (lane < 16) red[(t >> 6) * 16 + n] = s;
  __syncthreads();
  if (t < 16) t2e[(size_t)row * 64 + t] =
      f2bf(LORA_SCALE * (red[t] + red[t + 16] + red[t + 32] + red[t + 48]));
}

// ---------------- Fused SwiGLU (bf16 in) + LoRA down-proj ----------------
__global__ void silu_lora_kernel(const unsigned short* __restrict__ gub, const float* __restrict__ a,
                                 unsigned short* __restrict__ gbf, unsigned short* __restrict__ t2e) {
  int row = blockIdx.x, t = threadIdx.x;  // 256 threads
  int lane = t & 63;
  __shared__ float xs[F];   // 16KB
  __shared__ float red[64];
#pragma unroll
  for (int i2 = 0; i2 < 2; ++i2) {
    int idx = i2 * 256 + t;   // 512 chunks of 8 bf16
    uint4 gv = ((const uint4*)(gub + (size_t)row * RS_GU))[idx];
    uint4 uv = ((const uint4*)(gub + (size_t)row * RS_GU + F))[idx];
    const unsigned* gw = (const unsigned*)&gv;
    const unsigned* uw = (const unsigned*)&uv;
    unsigned short go[8];
#pragma unroll
    for (int q = 0; q < 4; ++q) {
      float g0 = bf2f((unsigned short)(gw[q] & 0xffff)), g1 = bf2f((unsigned short)(gw[q] >> 16));
      float u0 = bf2f((unsigned short)(uw[q] & 0xffff)), u1 = bf2f((unsigned short)(uw[q] >> 16));
      float r0 = g0 / (1.0f + __expf(-g0)) * u0;
      float r1 = g1 / (1.0f + __expf(-g1)) * u1;
      xs[idx * 8 + q * 2] = r0; xs[idx * 8 + q * 2 + 1] = r1;
      go[q * 2] = f2bf(r0); go[q * 2 + 1] = f2bf(r1);
    }
    *(uint4*)(gbf + (size_t)row * F + idx * 8) = *(const uint4*)go;
  }
  if (t >= 16 && t < 64) t2e[(size_t)row * 64 + t] = 0;
  __syncthreads();
  int n = t & 15, g = t >> 4;
  float s = 0.0f;
  for (int k = g; k < F; k += 16) s = fmaf(xs[k], a[k * 16 + n], s);
  s += __shfl_xor(s, 16);
  s += __shfl_xor(s, 32);
  if (lane < 16) red[(t >> 6) * 16 + n] = s;
  __syncthreads();
  if (t < 16) t2e[(size_t)row * 64 + t] =
      f2bf(LORA_SCALE * (red[t] + red[t + 16] + red[t + 32] + red[t + 48]));
}

// ---------------- Merged bext builder (all layers, one dispatch) ----------------
struct BD { const float* p0; const float* p1; const float* p2;
            unsigned short* dst; int NA; int logW; int nelem; };
struct BDs { BD d[8]; };
__global__ void bext_many_kernel(BDs da) {
  int gid = blockIdx.x * 256 + threadIdx.x;
  int di = 0;
  while (gid >= da.d[di].nelem) { gid -= da.d[di].nelem; ++di; }
  const BD dd = da.d[di];
  int n = gid >> 6, kk = gid & 63;
  int W = 1 << dd.logW;
  int sel = n >> dd.logW;
  const float* bp = (sel == 0) ? dd.p0 : (sel == 1) ? dd.p1 : dd.p2;
  float v = 0.0f;
  if ((kk >> 4) == sel && sel < dd.NA)
    v = bp[(size_t)(kk & 15) * W + (n & (W - 1))];
  dd.dst[(size_t)n * 64 + kk] = f2bf(v);
}

// ---------------- Merged f32 [K,N] -> bf16 [N,K] transposes (layer weights only) ----------------
// 128k x 64n tile, global_load_lds staged (structural-floor verdict: ~2.4TB/s scatter-bound).
struct TD { const float* src; unsigned short* dst; int K; int N; int nblk; };
struct TDs { TD d[14]; };
__global__ __launch_bounds__(256) void transpose_many_kernel(TDs da) {
  __shared__ __align__(16) float tile[128 * 64];   // 32KB
  int bid = blockIdx.x;
  int di = 0;
  while (bid >= da.d[di].nblk) { bid -= da.d[di].nblk; ++di; }
  const TD dd = da.d[di];
  int nbx = dd.N >> 6;
  int n0 = (bid % nbx) * 64, k0 = (bid / nbx) * 128;
  int t = threadIdx.x;
#pragma unroll
  for (int i = 0; i < 8; ++i) {
    int s = i * 256 + t;              // slot: 16B granules, lane-contiguous
    int k = s >> 4, cp = s & 15;
    int c = cp ^ (k >> 3);            // inverse-swizzled global chunk
    load_lds16(dd.src + (size_t)(k0 + k) * dd.N + n0 + c * 4, &tile[s * 4]);
  }
  asm volatile("s_waitcnt vmcnt(0)" ::: "memory");
  __builtin_amdgcn_s_barrier();
#pragma unroll
  for (int j2 = 0; j2 < 4; ++j2) {
    int flat = j2 * 256 + t;
    int n = flat >> 4, kc = flat & 15;
    int cs = ((n >> 2) ^ kc) << 2;
    unsigned short o8[8];
#pragma unroll
    for (int q = 0; q < 8; ++q) {
      int k = kc * 8 + q;
      o8[q] = f2bf(tile[k * 64 + cs + (n & 3)]);
    }
    *(uint4*)(dd.dst + (size_t)(n0 + n) * dd.K + k0 + kc * 8) = *(const uint4*)o8;
  }
}

// ---------------- bf16 MFMA GEMM: depth-2 pipeline + T2 swizzle + LoRA K-ext ----------------
// BM in {64,128}, BN in {64,128}. OM: 0 = f32 out (opt ACC), 1 = bf16 out,
// 2 = bf16 out + RoPE on cols < 2*D (qkv; requires BN=128).
template <int BM, int BN, bool ACC, bool EXT, int OM>
__global__ __launch_bounds__(256) void gemm_bf16_kernel(
    const unsigned short* __restrict__ A, const unsigned short* __restrict__ Bt,
    void* __restrict__ Cp, int M, int N, int K,
    const unsigned short* __restrict__ Ae, const unsigned short* __restrict__ Be,
    const float* __restrict__ cosb, const float* __restrict__ sinb) {
  constexpr int WC = (BM == 64 || BN == 128) ? 2 : 1;  // wave cols
  constexpr int WR = 4 / WC;                            // wave rows
  constexpr int RW = BM / WR;                           // rows per wave
  constexpr int MI = RW / 16;
  constexpr int CN = BN / WC;                           // cols per wave
  constexpr int NI = CN / 16;
  constexpr int ACH = BM / 32;
  constexpr int BCH = BN / 32;
  constexpr int NLOADS = ACH + BCH;
  __shared__ __align__(16) unsigned short As[2][BM * 64];
  __shared__ __align__(16) unsigned short Bs[2][BN * 64];
  int t = threadIdx.x;
  int lane = t & 63, wave = t >> 6;
  int wr = wave / WC, wc = wave % WC;
  int MT = gridDim.y, NT = gridDim.x;
  int nwg = MT * NT;
  int orig = blockIdx.y * NT + blockIdx.x;
  int qq = nwg >> 3, rr8 = nwg & 7;
  int xcd = orig & 7, pos = orig >> 3;
  int wg = (xcd < rr8) ? (xcd * (qq + 1) + pos) : (rr8 * (qq + 1) + (xcd - rr8) * qq + pos);
  int m0 = (wg % MT) * BM, n0 = (wg / MT) * BN;
  int fr = lane & 15, fq = lane >> 4;
  int xorv = fr & 7;
  f32x4 acc[MI][NI] = {};
  int kIters = K / 64;
  int nIters = EXT ? kIters + 1 : kIters;

  auto STAGE = [&](int it, int buf) {
    bool ext = EXT && (it == kIters);
    int k0 = it * 64;
#pragma unroll
    for (int c = 0; c < ACH; ++c) {
      int i = c * 256 + t;
      int row = i >> 3, c8 = i & 7;
      int sc = (c8 ^ (row & 7)) * 8;
      const unsigned short* src = ext ? (Ae + (size_t)(m0 + row) * 64 + sc)
                                      : (A + (size_t)(m0 + row) * K + k0 + sc);
      load_lds16(src, &As[buf][i * 8]);
    }
#pragma unroll
    for (int c = 0; c < BCH; ++c) {
      int i = c * 256 + t;
      int row = i >> 3, c8 = i & 7;
      int sc = (c8 ^ (row & 7)) * 8;
      const unsigned short* src = ext ? (Be + (size_t)(n0 + row) * 64 + sc)
                                      : (Bt + (size_t)(n0 + row) * K + k0 + sc);
      load_lds16(src, &Bs[buf][i * 8]);
    }
  };

  STAGE(0, 0);
  if (nIters > 1) STAGE(1, 1);
  int cur = 0;
  for (int it = 0; it < nIters; ++it) {
    if (it + 1 < nIters) {
      if constexpr (NLOADS == 8)      asm volatile("s_waitcnt vmcnt(8)" ::: "memory");
      else if constexpr (NLOADS == 6) asm volatile("s_waitcnt vmcnt(6)" ::: "memory");
      else                            asm volatile("s_waitcnt vmcnt(4)" ::: "memory");
    } else {
      asm volatile("s_waitcnt vmcnt(0)" ::: "memory");
    }
    __builtin_amdgcn_s_barrier();
#pragma unroll
    for (int kk = 0; kk < 2; ++kk) {
      bf16x8 af[MI], bfr[NI];
#pragma unroll
      for (int mi = 0; mi < MI; ++mi)
        af[mi] = *(const bf16x8*)(&As[cur][(wr * RW + mi * 16 + fr) * 64 + (((kk * 4 + fq) ^ xorv) << 3)]);
#pragma unroll
      for (int ni = 0; ni < NI; ++ni)
        bfr[ni] = *(const bf16x8*)(&Bs[cur][(wc * CN + ni * 16 + fr) * 64 + (((kk * 4 + fq) ^ xorv) << 3)]);
#pragma unroll
      for (int mi = 0; mi < MI; ++mi)
#pragma unroll
        for (int ni = 0; ni < NI; ++ni)
          acc[mi][ni] = __builtin_amdgcn_mfma_f32_16x16x32_bf16(af[mi], bfr[ni], acc[mi][ni], 0, 0, 0);
    }
    __builtin_amdgcn_s_barrier();
    if (it + 2 < nIters) STAGE(it + 2, cur);
    cur ^= 1;
  }
  // epilogue (C/D layout: col=lane&15, row=(lane>>4)*4+j)
  if constexpr (OM == 0) {
    float* C = (float*)Cp;
#pragma unroll
    for (int mi = 0; mi < MI; ++mi)
#pragma unroll
      for (int ni = 0; ni < NI; ++ni)
#pragma unroll
        for (int j = 0; j < 4; ++j) {
          int r = m0 + wr * RW + mi * 16 + fq * 4 + j;
          int cl = n0 + wc * CN + ni * 16 + fr;
          size_t idx = (size_t)r * N + cl;
          float v = acc[mi][ni][j];
          C[idx] = ACC ? C[idx] + v : v;
        }
  } else {
    unsigned short* Cb = (unsigned short*)Cp;
#pragma unroll
    for (int mi = 0; mi < MI; ++mi)
#pragma unroll
      for (int j = 0; j < 4; ++j) {
        int r = m0 + wr * RW + mi * 16 + fq * 4 + j;
        if constexpr (OM == 2) {
          int s = r & (S - 1);
#pragma unroll
          for (int ni = 0; ni < 2; ++ni) {
            int cl0 = n0 + wc * CN + ni * 16 + fr;
            int cl1 = cl0 + 32;
            float x0 = acc[mi][ni][j], x1 = acc[mi][ni + 2][j];
            if (cl0 < 2 * D) {
              int dh = cl0 & 63;
              float cz = cosb[s * DH + dh], sz = sinb[s * DH + dh];
              float y0 = x0 * cz - x1 * sz;
              float y1 = x1 * cz + x0 * sz;
              x0 = y0; x1 = y1;
            }
            Cb[(size_t)r * N + cl0] = f2bf(x0);
            Cb[(size_t)r * N + cl1] = f2bf(x1);
          }
        } else {
#pragma unroll
          for (int ni = 0; ni < NI; ++ni) {
            int cl = n0 + wc * CN + ni * 16 + fr;
            Cb[(size_t)r * N + cl] = f2bf(acc[mi][ni][j]);
          }
        }
      }
  }
}

// ---------------- 256x256 lm GEMM, B = f32 [K,N] consumed directly ----------------
// A bf16 [M,K] via global_load_lds (T2 source swizzle, unchanged read path).
// B: per K-step [64k][256n] f32: coalesced 1KB-row reg loads (wave = k-row), packed to
// bf16x2 (k,k+1), ds_write_b32 into Bs with row stride 144B and chunk swizzle
// (k>>3)^(n&7)^((n>>3)&7). T14 split: B_LOAD(it+1) issued before MFMA(it); counted vmcnt.
__global__ __launch_bounds__(512) void gemm256f_kernel(
    const unsigned short* __restrict__ A, const float* __restrict__ Bsrc,
    float* __restrict__ C, int M, int N, int K) {
  __shared__ __align__(16) unsigned short As[256 * 64];  // 32KB
  __shared__ __align__(16) char BsB[256 * 144];          // 36KB, row stride 144B
  int t = threadIdx.x;
  int lane = t & 63, wave = t >> 6;
  int wr = wave >> 2, wc = wave & 3;
  int MT = gridDim.y, NT = gridDim.x;
  int nwg = MT * NT;
  int orig = blockIdx.y * NT + blockIdx.x;
  int qq = nwg >> 3, rr8 = nwg & 7;
  int xcd = orig & 7, pos = orig >> 3;
  int wg = (xcd < rr8) ? (xcd * (qq + 1) + pos) : (rr8 * (qq + 1) + (xcd - rr8) * qq + pos);
  int m0 = (wg % MT) * 256, n0 = (wg / MT) * 256;
  int fr = lane & 15, fq = lane >> 4;
  int xorv = fr & 7;
  f32x4 acc[8][4] = {};
  int kIters = K / 64;
  float4 blo[4], bhi[4];
  int kq = wave;            // wave owns k-rows {kq*2, kq*2+1} + i*16
  int n4 = lane;            // n-quad

  auto B_LOAD = [&](int it) {
    int k0 = it * 64;
#pragma unroll
    for (int i = 0; i < 4; ++i) {
      int kb = i * 16 + kq * 2;
      blo[i] = *(const float4*)(Bsrc + (size_t)(k0 + kb) * N + n0 + n4 * 4);
      bhi[i] = *(const float4*)(Bsrc + (size_t)(k0 + kb + 1) * N + n0 + n4 * 4);
    }
  };
  auto B_WRITE = [&]() {
#pragma unroll
    for (int i = 0; i < 4; ++i) {
      int kb = i * 16 + kq * 2;
      int ch0 = kb >> 3, koff = kb & 7;   // koff even
      const float* lo = (const float*)&blo[i];
      const float* hi = (const float*)&bhi[i];
#pragma unroll
      for (int j = 0; j < 4; ++j) {
        int n = n4 * 4 + j;
        int swz = (n & 7) ^ ((n >> 3) & 7);
        unsigned pk = (unsigned)f2bf(lo[j]) | ((unsigned)f2bf(hi[j]) << 16);
        *(unsigned*)(BsB + n * 144 + ((ch0 ^ swz) << 4) + koff * 2) = pk;
      }
    }
  };
  auto A_STAGE = [&](int it) {
    int k0 = it * 64;
#pragma unroll
    for (int c = 0; c < 4; ++c) {
      int i = c * 512 + t;
      int row = i >> 3, c8 = i & 7;
      int sc = (c8 ^ (row & 7)) * 8;
      load_lds16(A + (size_t)(m0 + row) * K + k0 + sc, &As[i * 8]);
    }
  };

  B_LOAD(0);
  for (int it = 0; it < kIters; ++it) {
    __syncthreads();                 // prev readers of As/BsB done
    A_STAGE(it);                     // 4 gload_lds (newest)
    asm volatile("s_waitcnt vmcnt(4)" ::: "memory");   // B(it) regs ready; A(it) in flight
    B_WRITE();
    if (it + 1 < kIters) {
      B_LOAD(it + 1);                // 8 loads issued early (hide under MFMA)
      asm volatile("s_waitcnt vmcnt(8)" ::: "memory"); // drain A(it); keep B(it+1) flying
    } else {
      asm volatile("s_waitcnt vmcnt(0)" ::: "memory");
    }
    __syncthreads();                 // ds_writes + LDS visible
    __builtin_amdgcn_s_setprio(1);
#pragma unroll
    for (int kk = 0; kk < 2; ++kk) {
      bf16x8 af[8], bfr[4];
#pragma unroll
      for (int mi = 0; mi < 8; ++mi)
        af[mi] = *(const bf16x8*)(&As[(wr * 128 + mi * 16 + fr) * 64 + (((kk * 4 + fq) ^ xorv) << 3)]);
#pragma unroll
      for (int ni = 0; ni < 4; ++ni) {
        int n = wc * 64 + ni * 16 + fr;
        int swz = (n & 7) ^ ((n >> 3) & 7);
        bfr[ni] = *(const bf16x8*)(BsB + n * 144 + (((kk * 4 + fq) ^ swz) << 4));
      }
#pragma unroll
      for (int mi = 0; mi < 8; ++mi)
#pragma unroll
        for (int ni = 0; ni < 4; ++ni)
          acc[mi][ni] = __builtin_amdgcn_mfma_f32_16x16x32_bf16(af[mi], bfr[ni], acc[mi][ni], 0, 0, 0);
    }
    __builtin_amdgcn_s_setprio(0);
  }
#pragma unroll
  for (int mi = 0; mi < 8; ++mi)
#pragma unroll
    for (int ni = 0; ni < 4; ++ni)
#pragma unroll
      for (int j = 0; j < 4; ++j) {
        int r = m0 + wr * 128 + mi * 16 + fq * 4 + j;
        int cl = n0 + wc * 64 + ni * 16 + fr;
        C[(size_t)r * N + cl] = acc[mi][ni][j];
      }
}

// ---------------- Flash attention, bf16 MFMA (4 waves, QBLK=64; paired V staging) ----------------
__global__ __launch_bounds__(256) void attn_mfma_kernel(
    const unsigned short* __restrict__ qkvb, const int* __restrict__ amask,
    unsigned short* __restrict__ o) {
  __shared__ unsigned short Qs[64 * 72];
  __shared__ unsigned short Ks[64 * 72];
  __shared__ unsigned short Vt[64 * 72];   // [dh][key]
  __shared__ unsigned short Ps[4][16 * 72];
  __shared__ float msk[64];
  int bid = blockIdx.x;
  int qt = bid & 7, hh = (bid >> 3) & (H - 1), b = bid >> 7;
  int t = threadIdx.x;
  int lane = t & 63, w = t >> 6;
  int fr = lane & 15, fq = lane >> 4;
  size_t rowbase = (size_t)b * S;
  int q0 = qt * 64;
  const float scale = 0.125f;  // 1/sqrt(64)
#pragma unroll
  for (int c = 0; c < 2; ++c) {
    int i = c * 256 + t;
    int row = i >> 3, ch = i & 7;
    *(uint4*)(Qs + row * 72 + ch * 8) =
        *(const uint4*)(qkvb + (rowbase + q0 + row) * RS_QKV + hh * DH + ch * 8);
  }
  f32x4 oacc[4] = {};
  float m_old[4] = {-1e30f, -1e30f, -1e30f, -1e30f};
  float l[4] = {};
  int qbase = q0 + w * 16;
  for (int kt = 0; kt <= qt; ++kt) {
    int kk0 = kt * 64;
#pragma unroll
    for (int c = 0; c < 2; ++c) {
      int i = c * 256 + t;
      int row = i >> 3, ch = i & 7;
      uint4 kv = *(const uint4*)(qkvb + (rowbase + kk0 + row) * RS_QKV + D + hh * DH + ch * 8);
      *(uint4*)(Ks + row * 72 + ch * 8) = kv;
    }
#pragma unroll
    for (int c = 0; c < 2; ++c) {
      int idx = c * 256 + t;
      int rp = idx >> 4, dg = idx & 15;
      const unsigned short* vsrc = qkvb + (rowbase + kk0 + rp * 2) * RS_QKV + 2 * D + hh * DH + dg * 4;
      uint2 lo = *(const uint2*)vsrc;
      uint2 hi = *(const uint2*)(vsrc + RS_QKV);
      const unsigned short* ls = (const unsigned short*)&lo;
      const unsigned short* hs = (const unsigned short*)&hi;
#pragma unroll
      for (int q = 0; q < 4; ++q) {
        unsigned pk = (unsigned)ls[q] | ((unsigned)hs[q] << 16);
        *(unsigned*)(Vt + (dg * 4 + q) * 72 + rp * 2) = pk;
      }
    }
    if (t < 64) msk[t] = (amask[b * S + kk0 + t] > 0) ? 0.0f : -1e9f;
    __syncthreads();
    bf16x8 aq[2];
    aq[0] = *(const bf16x8*)(Qs + (w * 16 + fr) * 72 + fq * 8);
    aq[1] = *(const bf16x8*)(Qs + (w * 16 + fr) * 72 + 32 + fq * 8);
    f32x4 sacc[4];
#pragma unroll
    for (int ct = 0; ct < 4; ++ct) {
      bf16x8 bk0 = *(const bf16x8*)(Ks + (ct * 16 + fr) * 72 + fq * 8);
      bf16x8 bk1 = *(const bf16x8*)(Ks + (ct * 16 + fr) * 72 + 32 + fq * 8);
      f32x4 z = {};
      z = __builtin_amdgcn_mfma_f32_16x16x32_bf16(aq[0], bk0, z, 0, 0, 0);
      sacc[ct] = __builtin_amdgcn_mfma_f32_16x16x32_bf16(aq[1], bk1, z, 0, 0, 0);
    }
    float sv[4][4];
#pragma unroll
    for (int ct = 0; ct < 4; ++ct) {
      int kg = kk0 + ct * 16 + fr;
      float mk = msk[ct * 16 + fr];
#pragma unroll
      for (int j = 0; j < 4; ++j) {
        int qg = qbase + fq * 4 + j;
        float s = sacc[ct][j] * scale + mk;
        sv[ct][j] = (kg > qg) ? -1e9f : s;
      }
    }
    float mnew[4], f[4], rsum[4];
#pragma unroll
    for (int j = 0; j < 4; ++j) {
      float mt = fmaxf(fmaxf(sv[0][j], sv[1][j]), fmaxf(sv[2][j], sv[3][j]));
      for (int off = 1; off < 16; off <<= 1) mt = fmaxf(mt, __shfl_xor(mt, off));
      mnew[j] = fmaxf(m_old[j], mt);
      f[j] = __expf(m_old[j] - mnew[j]);
      float rs = 0.0f;
#pragma unroll
      for (int ct = 0; ct < 4; ++ct) {
        float e = __expf(sv[ct][j] - mnew[j]);
        sv[ct][j] = e;
        rs += e;
      }
      for (int off = 1; off < 16; off <<= 1) rs += __shfl_xor(rs, off);
      rsum[j] = rs;
      l[j] = l[j] * f[j] + rsum[j];
      m_old[j] = mnew[j];
#pragma unroll
      for (int dt = 0; dt < 4; ++dt) oacc[dt][j] *= f[j];
    }
#pragma unroll
    for (int ct = 0; ct < 4; ++ct)
#pragma unroll
      for (int j = 0; j < 4; ++j)
        Ps[w][(fq * 4 + j) * 72 + ct * 16 + fr] = f2bf(sv[ct][j]);
    __syncthreads();
    bf16x8 pa[2];
    pa[0] = *(const bf16x8*)(&Ps[w][fr * 72 + fq * 8]);
    pa[1] = *(const bf16x8*)(&Ps[w][fr * 72 + 32 + fq * 8]);
#pragma unroll
    for (int dt = 0; dt < 4; ++dt) {
      bf16x8 vb0 = *(const bf16x8*)(Vt + (dt * 16 + fr) * 72 + fq * 8);
      bf16x8 vb1 = *(const bf16x8*)(Vt + (dt * 16 + fr) * 72 + 32 + fq * 8);
      oacc[dt] = __builtin_amdgcn_mfma_f32_16x16x32_bf16(pa[0], vb0, oacc[dt], 0, 0, 0);
      oacc[dt] = __builtin_amdgcn_mfma_f32_16x16x32_bf16(pa[1], vb1, oacc[dt], 0, 0, 0);
    }
    __syncthreads();
  }
#pragma unroll
  for (int j = 0; j < 4; ++j) {
    float rinv = 1.0f / l[j];
    int qrow = qbase + fq * 4 + j;
#pragma unroll
    for (int dt = 0; dt < 4; ++dt)
      o[(rowbase + qrow) * D + hh * DH + dt * 16 + fr] = f2bf(oacc[dt][j] * rinv);
  }
}

extern "C" void kernel_launch(void* const* d_in, const int* in_sizes, int n_in,
                              void* d_out, int out_size, void* d_ws, size_t ws_size,
                              hipStream_t stream) {
  const int*   ids     = (const int*)d_in[0];
  const int*   amask   = (const int*)d_in[1];
  const float* emb     = (const float*)d_in[2];
  const float* ln1     = (const float*)d_in[3];
  const float* ln2     = (const float*)d_in[4];
  const float* wq = (const float*)d_in[5],  *aq = (const float*)d_in[6],  *bq = (const float*)d_in[7];
  const float* wk = (const float*)d_in[8],  *ak = (const float*)d_in[9],  *bk = (const float*)d_in[10];
  const float* wv = (const float*)d_in[11], *av = (const float*)d_in[12], *bv = (const float*)d_in[13];
  const float* wo = (const float*)d_in[14], *ao = (const float*)d_in[15], *bo = (const float*)d_in[16];
  const float* wg = (const float*)d_in[17], *ag = (const float*)d_in[18], *bg = (const float*)d_in[19];
  const float* wu = (const float*)d_in[20], *au = (const float*)d_in[21], *bu = (const float*)d_in[22];
  const float* wd = (const float*)d_in[23], *ad = (const float*)d_in[24], *bd = (const float*)d_in[25];
  const float* final_ln  = (const float*)d_in[26];
  const float* lm_head_w = (const float*)d_in[27];
  const float* value_w   = (const float*)d_in[28];
  const float* value_b   = (const float*)d_in[29];

  float* out    = (float*)d_out;
  float* logits = out;
  float* values = out + (size_t)BS * V;

  // ---- workspace ----
  float* Wf = (float*)d_ws;
  float* cosb = Wf; Wf += S * DH;
  float* sinb = Wf; Wf += S * DH;
  float* h    = Wf; Wf += (size_t)BS * D;
  unsigned short* Wb = (unsigned short*)Wf;
  unsigned short* x_bf  = Wb; Wb += (size_t)BS * D;
  unsigned short* t2e   = Wb; Wb += (size_t)BS * 64;
  unsigned short* qg    = Wb; Wb += (size_t)BS * F;      // shared: qkv_bf (3D) / gbf (F)
  unsigned short* gu_bf = Wb; Wb += (size_t)BS * RS_GU;  // obf aliases its head
  unsigned short* wqkvT = Wb; Wb += (size_t)L * 3 * D * D;
  unsigned short* woT   = Wb; Wb += (size_t)L * D * D;
  unsigned short* wguT  = Wb; Wb += (size_t)L * 2 * D * F;
  unsigned short* wdT   = Wb; Wb += (size_t)L * F * D;
  unsigned short* beQKV = Wb; Wb += (size_t)L * 3 * D * 64;
  unsigned short* beO   = Wb; Wb += (size_t)L * D * 64;
  unsigned short* beGU  = Wb; Wb += (size_t)L * 2 * F * 64;
  unsigned short* beD   = Wb; Wb += (size_t)L * D * 64;
  unsigned short* qkv_bf = qg;                 // [BS][3D]
  unsigned short* gbf    = qg;                 // [BS][F]
  unsigned short* obf    = gu_bf;              // [BS][D]

  // ---- merged weight transposes (layer weights only; lm consumed f32 in-GEMM) ----
  TDs td; int tblocks = 0; int di = 0;
  auto addT = [&](const float* s, unsigned short* dp, int K_, int N_) {
    td.d[di] = {s, dp, K_, N_, (K_ / 128) * (N_ / 64)};
    tblocks += td.d[di].nblk; ++di;
  };
  for (int l = 0; l < L; ++l) {
    size_t DD = (size_t)D * D, DF = (size_t)D * F;
    addT(wq + l * DD, wqkvT + (size_t)l * 3 * DD, D, D);
    addT(wk + l * DD, wqkvT + (size_t)l * 3 * DD + DD, D, D);
    addT(wv + l * DD, wqkvT + (size_t)l * 3 * DD + 2 * DD, D, D);
    addT(wo + l * DD, woT + l * DD, D, D);
    addT(wg + l * DF, wguT + (size_t)l * 2 * DF, D, F);
    addT(wu + l * DF, wguT + (size_t)l * 2 * DF + DF, D, F);
    addT(wd + l * DF, wdT + l * DF, F, D);
  }
  transpose_many_kernel<<<dim3(tblocks), 256, 0, stream>>>(td);

  // ---- merged bext (one dispatch) ----
  BDs bd2; int belems = 0; di = 0;
  auto addB = [&](const float* p0, const float* p1, const float* p2,
                  unsigned short* dst, int NA, int logW, int N_) {
    bd2.d[di] = {p0, p1, p2, dst, NA, logW, N_ * 64};
    belems += N_ * 64; ++di;
  };
  for (int l = 0; l < L; ++l) {
    size_t oRD = (size_t)l * R * D, oRF = (size_t)l * R * F;
    addB(bq + oRD, bk + oRD, bv + oRD, beQKV + (size_t)l * 3 * D * 64, 3, 10, 3 * D);
    addB(bo + oRD, nullptr, nullptr,   beO   + (size_t)l * D * 64,     1, 10, D);
    addB(bg + oRF, bu + oRF, nullptr,  beGU  + (size_t)l * 2 * F * 64, 2, 12, 2 * F);
    addB(bd + oRD, nullptr, nullptr,   beD   + (size_t)l * D * 64,     1, 10, D);
  }
  bext_many_kernel<<<dim3(belems / 256), 256, 0, stream>>>(bd2);

  rope_cache_kernel<<<dim3(S), dim3(32), 0, stream>>>(cosb, sinb);
  embed_kernel<<<dim3(BS), dim3(256), 0, stream>>>(ids, emb, h);

  for (int l = 0; l < L; ++l) {
    size_t DD = (size_t)D * D, DF = (size_t)D * F;
    size_t oDR = (size_t)l * D * R, oFR = (size_t)l * F * R;

    // ---- attention block ----
    { Ptr3 ap = {{aq + oDR, ak + oDR, av + oDR}};
      rms_lora_kernel<3><<<dim3(BS), 256, 0, stream>>>(h, ln1 + (size_t)l * D, ap, x_bf, t2e); }
    gemm_bf16_kernel<64, 128, false, true, 2><<<dim3(3 * D / 128, BS / 64), 256, 0, stream>>>(
        x_bf, wqkvT + (size_t)l * 3 * DD, qkv_bf, BS, 3 * D, D,
        t2e, beQKV + (size_t)l * 3 * D * 64, cosb, sinb);

    attn_mfma_kernel<<<dim3(B * H * (S / 64)), 256, 0, stream>>>(qkv_bf, amask, obf);

    lora_o_kernel<<<dim3(BS), 256, 0, stream>>>(obf, ao + oDR, t2e);
    gemm_bf16_kernel<64, 64, true, true, 0><<<dim3(D / 64, BS / 64), 256, 0, stream>>>(
        obf, woT + l * DD, h, BS, D, D, t2e, beO + (size_t)l * D * 64, nullptr, nullptr);

    // ---- MLP block ----
    { Ptr3 ap = {{ag + oDR, au + oDR, nullptr}};
      rms_lora_kernel<2><<<dim3(BS), 256, 0, stream>>>(h, ln2 + (size_t)l * D, ap, x_bf, t2e); }
    gemm_bf16_kernel<128, 128, false, true, 1><<<dim3(2 * F / 128, BS / 128), 256, 0, stream>>>(
        x_bf, wguT + (size_t)l * 2 * DF, gu_bf, BS, 2 * F, D,
        t2e, beGU + (size_t)l * 2 * F * 64, nullptr, nullptr);

    silu_lora_kernel<<<dim3(BS), 256, 0, stream>>>(gu_bf, ad + oFR, gbf, t2e);

    gemm_bf16_kernel<64, 64, true, true, 0><<<dim3(D / 64, BS / 64), 256, 0, stream>>>(
        gbf, wdT + l * DF, h, BS, D, F, t2e, beD + (size_t)l * D * 64, nullptr, nullptr);
  }

  // ---- final norm + fused value head + lm head (f32 B direct) ----
  rmsnorm_value_kernel<<<dim3(BS), 256, 0, stream>>>(h, final_ln, value_w, value_b, x_bf, values);
  gemm256f_kernel<<<dim3(V / 256, BS / 256), 512, 0, stream>>>(x_bf, lm_head_w, logits, BS, V, D);
}

// Round 15
// 902.194 us; speedup vs baseline: 1.1147x; 1.0102x over previous
//
#include <hip/hip_runtime.h>
#include <math.h>

// LLaMA-style decoder forward: B=2 S=512 D=1024 H=16 F=4096 V=32000 L=2 R=16
constexpr int B = 2, S = 512, D = 1024, H = 16, F = 4096, V = 32000, L = 2, R = 16, DH = 64;
constexpr int BS = B * S;          // 1024 rows
constexpr float LORA_SCALE = 2.0f; // alpha/r
constexpr float EPS = 1e-5f;
constexpr int RS_QKV = 3 * D;      // fused qkv row stride (ushorts)
constexpr int RS_GU  = 2 * F;      // fused g|u row stride (ushorts)

typedef __attribute__((ext_vector_type(8))) __bf16 bf16x8;
typedef __attribute__((ext_vector_type(4))) float f32x4;

__device__ __forceinline__ unsigned short f2bf(float f) {
  unsigned u = __builtin_bit_cast(unsigned, f);
  unsigned r = (u + 0x7FFFu + ((u >> 16) & 1u)) >> 16;  // RNE
  return (unsigned short)r;
}
__device__ __forceinline__ float bf2f(unsigned short us) {
  return __builtin_bit_cast(float, (unsigned)us << 16);
}
__device__ __forceinline__ void load_lds16(const void* g, void* l) {
  __builtin_amdgcn_global_load_lds((const __attribute__((address_space(1))) void*)g,
                                   (__attribute__((address_space(3))) void*)l, 16, 0, 0);
}

struct Ptr3 { const float* p[3]; };

// ---------------- RoPE cache ----------------
__global__ void rope_cache_kernel(float* __restrict__ cosb, float* __restrict__ sinb) {
  int s = blockIdx.x, j = threadIdx.x;  // j in [0,32)
  float inv = __expf(-(float)j * (9.210340371976184f / 32.0f));
  float ang = (float)s * inv;
  float c = cosf(ang), sn = sinf(ang);
  cosb[s * DH + j] = c;  cosb[s * DH + j + 32] = c;
  sinb[s * DH + j] = sn; sinb[s * DH + j + 32] = sn;
}

// ---------------- Embedding gather ----------------
__global__ void embed_kernel(const int* __restrict__ ids, const float* __restrict__ emb,
                             float* __restrict__ h) {
  int row = blockIdx.x, t = threadIdx.x;
  int id = ids[row];
  ((float4*)(h + (size_t)row * D))[t] = ((const float4*)(emb + (size_t)id * D))[t];
}

// ---------------- RMSNorm -> bf16 + fused value head (final norm only) ----------------
__global__ void rmsnorm_value_kernel(const float* __restrict__ x, const float* __restrict__ w,
                                     const float* __restrict__ vw, const float* __restrict__ vb,
                                     unsigned short* __restrict__ y, float* __restrict__ values) {
  int row = blockIdx.x, t = threadIdx.x;
  int lane = t & 63;
  __shared__ float redw[4];
  __shared__ float redv[4];
  float4 xv = ((const float4*)(x + (size_t)row * D))[t];
  float ss = xv.x * xv.x + xv.y * xv.y + xv.z * xv.z + xv.w * xv.w;
#pragma unroll
  for (int off = 1; off < 64; off <<= 1) ss += __shfl_xor(ss, off);
  if (lane == 0) redw[t >> 6] = ss;
  __syncthreads();
  float rinv = rsqrtf((redw[0] + redw[1] + redw[2] + redw[3]) * (1.0f / D) + EPS);
  float4 wv = ((const float4*)w)[t];
  float4 nx;
  nx.x = xv.x * rinv * wv.x; nx.y = xv.y * rinv * wv.y;
  nx.z = xv.z * rinv * wv.z; nx.w = xv.w * rinv * wv.w;
  ushort4 o;
  o.x = f2bf(nx.x); o.y = f2bf(nx.y); o.z = f2bf(nx.z); o.w = f2bf(nx.w);
  ((ushort4*)(y + (size_t)row * D))[t] = o;
  float4 vv = ((const float4*)vw)[t];
  float vd = nx.x * vv.x + nx.y * vv.y + nx.z * vv.z + nx.w * vv.w;
#pragma unroll
  for (int off = 1; off < 64; off <<= 1) vd += __shfl_xor(vd, off);
  if (lane == 0) redv[t >> 6] = vd;
  __syncthreads();
  if (t == 0) values[row] = redv[0] + redv[1] + redv[2] + redv[3] + vb[0];
}

// ---------------- Fused RMSNorm + LoRA down-proj (shfl-reduce) ----------------
template <int NA>
__global__ void rms_lora_kernel(const float* __restrict__ hp, const float* __restrict__ w,
                                Ptr3 ap, unsigned short* __restrict__ xbf,
                                unsigned short* __restrict__ t2e) {
  int row = blockIdx.x, t = threadIdx.x;  // 256 threads
  int lane = t & 63;
  __shared__ float xs[D];
  __shared__ float red[256];
  __shared__ float redw[4];
  float4 xv = ((const float4*)(hp + (size_t)row * D))[t];
  float ss = xv.x * xv.x + xv.y * xv.y + xv.z * xv.z + xv.w * xv.w;
#pragma unroll
  for (int off = 1; off < 64; off <<= 1) ss += __shfl_xor(ss, off);
  if (lane == 0) redw[t >> 6] = ss;
  __syncthreads();
  float rinv = rsqrtf((redw[0] + redw[1] + redw[2] + redw[3]) * (1.0f / D) + EPS);
  float4 wv = ((const float4*)w)[t];
  float4 nx;
  nx.x = xv.x * rinv * wv.x; nx.y = xv.y * rinv * wv.y;
  nx.z = xv.z * rinv * wv.z; nx.w = xv.w * rinv * wv.w;
  xs[t * 4 + 0] = nx.x; xs[t * 4 + 1] = nx.y; xs[t * 4 + 2] = nx.z; xs[t * 4 + 3] = nx.w;
  ushort4 o;
  o.x = f2bf(nx.x); o.y = f2bf(nx.y); o.z = f2bf(nx.z); o.w = f2bf(nx.w);
  ((ushort4*)(xbf + (size_t)row * D))[t] = o;
  if (t >= NA * 16 && t < 64) t2e[(size_t)row * 64 + t] = 0;
  __syncthreads();
  int n = t & 15, g = t >> 4;
#pragma unroll
  for (int ad = 0; ad < NA; ++ad) {
    const float* a = ap.p[ad];
    float s = 0.0f;
    for (int k = g; k < D; k += 16) s = fmaf(xs[k], a[k * 16 + n], s);
    s += __shfl_xor(s, 16);
    s += __shfl_xor(s, 32);
    if (lane < 16) red[(t >> 6) * 16 + n] = s;
    __syncthreads();
    if (t < 16) t2e[(size_t)row * 64 + ad * 16 + t] =
        f2bf(LORA_SCALE * (red[t] + red[t + 16] + red[t + 32] + red[t + 48]));
    if (ad + 1 < NA) __syncthreads();
  }
}

// ---------------- LoRA down-proj from bf16 activation (o-proj) ----------------
__global__ void lora_o_kernel(const unsigned short* __restrict__ xb, const float* __restrict__ a,
                              unsigned short* __restrict__ t2e) {
  int row = blockIdx.x, t = threadIdx.x;  // 256 threads, K=D
  int lane = t & 63;
  __shared__ float xs[D];
  __shared__ float red[64];
  for (int k = t; k < D; k += 256) xs[k] = bf2f(xb[(size_t)row * D + k]);
  if (t >= 16 && t < 64) t2e[(size_t)row * 64 + t] = 0;
  __syncthreads();
  int n = t & 15, g = t >> 4;
  float s = 0.0f;
  for (int k = g; k < D; k += 16) s = fmaf(xs[k], a[k * 16 + n], s);
  s += __shfl_xor(s, 16);
  s += __shfl_xor(s, 32);
  if (lane < 16) red[(t >> 6) * 16 + n] = s;
  __syncthreads();
  if (t < 16) t2e[(size_t)row * 64 + t] =
      f2bf(LORA_SCALE * (red[t] + red[t + 16] + red[t + 32] + red[t + 48]));
}

// ---------------- Fused SwiGLU (bf16 in) + LoRA down-proj ----------------
__global__ void silu_lora_kernel(const unsigned short* __restrict__ gub, const float* __restrict__ a,
                                 unsigned short* __restrict__ gbf, unsigned short* __restrict__ t2e) {
  int row = blockIdx.x, t = threadIdx.x;  // 256 threads
  int lane = t & 63;
  __shared__ float xs[F];   // 16KB
  __shared__ float red[64];
#pragma unroll
  for (int i2 = 0; i2 < 2; ++i2) {
    int idx = i2 * 256 + t;   // 512 chunks of 8 bf16
    uint4 gv = ((const uint4*)(gub + (size_t)row * RS_GU))[idx];
    uint4 uv = ((const uint4*)(gub + (size_t)row * RS_GU + F))[idx];
    const unsigned* gw = (const unsigned*)&gv;
    const unsigned* uw = (const unsigned*)&uv;
    unsigned short go[8];
#pragma unroll
    for (int q = 0; q < 4; ++q) {
      float g0 = bf2f((unsigned short)(gw[q] & 0xffff)), g1 = bf2f((unsigned short)(gw[q] >> 16));
      float u0 = bf2f((unsigned short)(uw[q] & 0xffff)), u1 = bf2f((unsigned short)(uw[q] >> 16));
      float r0 = g0 / (1.0f + __expf(-g0)) * u0;
      float r1 = g1 / (1.0f + __expf(-g1)) * u1;
      xs[idx * 8 + q * 2] = r0; xs[idx * 8 + q * 2 + 1] = r1;
      go[q * 2] = f2bf(r0); go[q * 2 + 1] = f2bf(r1);
    }
    *(uint4*)(gbf + (size_t)row * F + idx * 8) = *(const uint4*)go;
  }
  if (t >= 16 && t < 64) t2e[(size_t)row * 64 + t] = 0;
  __syncthreads();
  int n = t & 15, g = t >> 4;
  float s = 0.0f;
  for (int k = g; k < F; k += 16) s = fmaf(xs[k], a[k * 16 + n], s);
  s += __shfl_xor(s, 16);
  s += __shfl_xor(s, 32);
  if (lane < 16) red[(t >> 6) * 16 + n] = s;
  __syncthreads();
  if (t < 16) t2e[(size_t)row * 64 + t] =
      f2bf(LORA_SCALE * (red[t] + red[t + 16] + red[t + 32] + red[t + 48]));
}

// ---------------- Merged bext builder (all layers, one dispatch) ----------------
struct BD { const float* p0; const float* p1; const float* p2;
            unsigned short* dst; int NA; int logW; int nelem; };
struct BDs { BD d[8]; };
__global__ void bext_many_kernel(BDs da) {
  int gid = blockIdx.x * 256 + threadIdx.x;
  int di = 0;
  while (gid >= da.d[di].nelem) { gid -= da.d[di].nelem; ++di; }
  const BD dd = da.d[di];
  int n = gid >> 6, kk = gid & 63;
  int W = 1 << dd.logW;
  int sel = n >> dd.logW;
  const float* bp = (sel == 0) ? dd.p0 : (sel == 1) ? dd.p1 : dd.p2;
  float v = 0.0f;
  if ((kk >> 4) == sel && sel < dd.NA)
    v = bp[(size_t)(kk & 15) * W + (n & (W - 1))];
  dd.dst[(size_t)n * 64 + kk] = f2bf(v);
}

// ---------------- Merged f32 [K,N] -> bf16 [N,K] transposes (layer weights only) ----------------
struct TD { const float* src; unsigned short* dst; int K; int N; int nblk; };
struct TDs { TD d[14]; };
__global__ __launch_bounds__(256) void transpose_many_kernel(TDs da) {
  __shared__ __align__(16) float tile[128 * 64];   // 32KB
  int bid = blockIdx.x;
  int di = 0;
  while (bid >= da.d[di].nblk) { bid -= da.d[di].nblk; ++di; }
  const TD dd = da.d[di];
  int nbx = dd.N >> 6;
  int n0 = (bid % nbx) * 64, k0 = (bid / nbx) * 128;
  int t = threadIdx.x;
#pragma unroll
  for (int i = 0; i < 8; ++i) {
    int s = i * 256 + t;              // slot: 16B granules, lane-contiguous
    int k = s >> 4, cp = s & 15;
    int c = cp ^ (k >> 3);            // inverse-swizzled global chunk
    load_lds16(dd.src + (size_t)(k0 + k) * dd.N + n0 + c * 4, &tile[s * 4]);
  }
  asm volatile("s_waitcnt vmcnt(0)" ::: "memory");
  __builtin_amdgcn_s_barrier();
#pragma unroll
  for (int j2 = 0; j2 < 4; ++j2) {
    int flat = j2 * 256 + t;
    int n = flat >> 4, kc = flat & 15;
    int cs = ((n >> 2) ^ kc) << 2;
    unsigned short o8[8];
#pragma unroll
    for (int q = 0; q < 8; ++q) {
      int k = kc * 8 + q;
      o8[q] = f2bf(tile[k * 64 + cs + (n & 3)]);
    }
    *(uint4*)(dd.dst + (size_t)(n0 + n) * dd.K + k0 + kc * 8) = *(const uint4*)o8;
  }
}

// ---------------- bf16 MFMA GEMM: depth-2 pipeline + T2 swizzle + LoRA K-ext ----------------
// BM in {64,128}, BN in {64,128}. OM: 0 = f32 out (opt ACC), 1 = bf16 out,
// 2 = bf16 out + RoPE on cols < 2*D (qkv; requires BN=128).
template <int BM, int BN, bool ACC, bool EXT, int OM>
__global__ __launch_bounds__(256) void gemm_bf16_kernel(
    const unsigned short* __restrict__ A, const unsigned short* __restrict__ Bt,
    void* __restrict__ Cp, int M, int N, int K,
    const unsigned short* __restrict__ Ae, const unsigned short* __restrict__ Be,
    const float* __restrict__ cosb, const float* __restrict__ sinb) {
  constexpr int WC = (BM == 64 || BN == 128) ? 2 : 1;  // wave cols
  constexpr int WR = 4 / WC;                            // wave rows
  constexpr int RW = BM / WR;                           // rows per wave
  constexpr int MI = RW / 16;
  constexpr int CN = BN / WC;                           // cols per wave
  constexpr int NI = CN / 16;
  constexpr int ACH = BM / 32;
  constexpr int BCH = BN / 32;
  constexpr int NLOADS = ACH + BCH;
  __shared__ __align__(16) unsigned short As[2][BM * 64];
  __shared__ __align__(16) unsigned short Bs[2][BN * 64];
  int t = threadIdx.x;
  int lane = t & 63, wave = t >> 6;
  int wr = wave / WC, wc = wave % WC;
  int MT = gridDim.y, NT = gridDim.x;
  int nwg = MT * NT;
  int orig = blockIdx.y * NT + blockIdx.x;
  int qq = nwg >> 3, rr8 = nwg & 7;
  int xcd = orig & 7, pos = orig >> 3;
  int wg = (xcd < rr8) ? (xcd * (qq + 1) + pos) : (rr8 * (qq + 1) + (xcd - rr8) * qq + pos);
  int m0 = (wg % MT) * BM, n0 = (wg / MT) * BN;
  int fr = lane & 15, fq = lane >> 4;
  int xorv = fr & 7;
  f32x4 acc[MI][NI] = {};
  int kIters = K / 64;
  int nIters = EXT ? kIters + 1 : kIters;

  auto STAGE = [&](int it, int buf) {
    bool ext = EXT && (it == kIters);
    int k0 = it * 64;
#pragma unroll
    for (int c = 0; c < ACH; ++c) {
      int i = c * 256 + t;
      int row = i >> 3, c8 = i & 7;
      int sc = (c8 ^ (row & 7)) * 8;
      const unsigned short* src = ext ? (Ae + (size_t)(m0 + row) * 64 + sc)
                                      : (A + (size_t)(m0 + row) * K + k0 + sc);
      load_lds16(src, &As[buf][i * 8]);
    }
#pragma unroll
    for (int c = 0; c < BCH; ++c) {
      int i = c * 256 + t;
      int row = i >> 3, c8 = i & 7;
      int sc = (c8 ^ (row & 7)) * 8;
      const unsigned short* src = ext ? (Be + (size_t)(n0 + row) * 64 + sc)
                                      : (Bt + (size_t)(n0 + row) * K + k0 + sc);
      load_lds16(src, &Bs[buf][i * 8]);
    }
  };

  STAGE(0, 0);
  if (nIters > 1) STAGE(1, 1);
  int cur = 0;
  for (int it = 0; it < nIters; ++it) {
    if (it + 1 < nIters) {
      if constexpr (NLOADS == 8)      asm volatile("s_waitcnt vmcnt(8)" ::: "memory");
      else if constexpr (NLOADS == 6) asm volatile("s_waitcnt vmcnt(6)" ::: "memory");
      else                            asm volatile("s_waitcnt vmcnt(4)" ::: "memory");
    } else {
      asm volatile("s_waitcnt vmcnt(0)" ::: "memory");
    }
    __builtin_amdgcn_s_barrier();
#pragma unroll
    for (int kk = 0; kk < 2; ++kk) {
      bf16x8 af[MI], bfr[NI];
#pragma unroll
      for (int mi = 0; mi < MI; ++mi)
        af[mi] = *(const bf16x8*)(&As[cur][(wr * RW + mi * 16 + fr) * 64 + (((kk * 4 + fq) ^ xorv) << 3)]);
#pragma unroll
      for (int ni = 0; ni < NI; ++ni)
        bfr[ni] = *(const bf16x8*)(&Bs[cur][(wc * CN + ni * 16 + fr) * 64 + (((kk * 4 + fq) ^ xorv) << 3)]);
#pragma unroll
      for (int mi = 0; mi < MI; ++mi)
#pragma unroll
        for (int ni = 0; ni < NI; ++ni)
          acc[mi][ni] = __builtin_amdgcn_mfma_f32_16x16x32_bf16(af[mi], bfr[ni], acc[mi][ni], 0, 0, 0);
    }
    __builtin_amdgcn_s_barrier();
    if (it + 2 < nIters) STAGE(it + 2, cur);
    cur ^= 1;
  }
  // epilogue (C/D layout: col=lane&15, row=(lane>>4)*4+j)
  if constexpr (OM == 0) {
    float* C = (float*)Cp;
#pragma unroll
    for (int mi = 0; mi < MI; ++mi)
#pragma unroll
      for (int ni = 0; ni < NI; ++ni)
#pragma unroll
        for (int j = 0; j < 4; ++j) {
          int r = m0 + wr * RW + mi * 16 + fq * 4 + j;
          int cl = n0 + wc * CN + ni * 16 + fr;
          size_t idx = (size_t)r * N + cl;
          float v = acc[mi][ni][j];
          C[idx] = ACC ? C[idx] + v : v;
        }
  } else {
    unsigned short* Cb = (unsigned short*)Cp;
#pragma unroll
    for (int mi = 0; mi < MI; ++mi)
#pragma unroll
      for (int j = 0; j < 4; ++j) {
        int r = m0 + wr * RW + mi * 16 + fq * 4 + j;
        if constexpr (OM == 2) {
          int s = r & (S - 1);
#pragma unroll
          for (int ni = 0; ni < 2; ++ni) {
            int cl0 = n0 + wc * CN + ni * 16 + fr;
            int cl1 = cl0 + 32;
            float x0 = acc[mi][ni][j], x1 = acc[mi][ni + 2][j];
            if (cl0 < 2 * D) {
              int dh = cl0 & 63;
              float cz = cosb[s * DH + dh], sz = sinb[s * DH + dh];
              float y0 = x0 * cz - x1 * sz;
              float y1 = x1 * cz + x0 * sz;
              x0 = y0; x1 = y1;
            }
            Cb[(size_t)r * N + cl0] = f2bf(x0);
            Cb[(size_t)r * N + cl1] = f2bf(x1);
          }
        } else {
#pragma unroll
          for (int ni = 0; ni < NI; ++ni) {
            int cl = n0 + wc * CN + ni * 16 + fr;
            Cb[(size_t)r * N + cl] = f2bf(acc[mi][ni][j]);
          }
        }
      }
  }
}

// ---------------- 128x128 lm GEMM, B = f32 [K,N] consumed directly ----------------
// v2 of r14's gemm256f. Fixes: (1) raw s_barrier + manual lgkmcnt(0) only -- r14's
// __syncthreads() emitted vmcnt(0) and drained the prefetch every iter; (2) As double-
// buffered, A(it+1) issued a full iter ahead; (3) 50KB LDS -> 3 blocks/CU TLP.
// B reg-loads: wave owns k rows 8w..8w+7; lane=(kp,nlo) holds k-pair rows for 8 n's ->
// b32 packs (k,k+1) with kp contributing low bank bits on ds_write.
__global__ __launch_bounds__(512) void gemm128f_kernel(
    const unsigned short* __restrict__ A, const float* __restrict__ Bsrc,
    float* __restrict__ C, int M, int N, int K) {
  __shared__ __align__(16) unsigned short As[2][128 * 64];  // 32KB
  __shared__ __align__(16) char BsB[128 * 144];             // 18KB
  int t = threadIdx.x;
  int lane = t & 63, wave = t >> 6;
  int wr = wave >> 2, wc = wave & 3;          // 2M x 4N waves; wave tile 64x32
  int MT = gridDim.y, NT = gridDim.x;
  int nwg = MT * NT;
  int orig = blockIdx.y * NT + blockIdx.x;
  int qq = nwg >> 3, rr8 = nwg & 7;
  int xcd = orig & 7, pos = orig >> 3;
  int wg = (xcd < rr8) ? (xcd * (qq + 1) + pos) : (rr8 * (qq + 1) + (xcd - rr8) * qq + pos);
  int m0 = (wg % MT) * 128, n0 = (wg / MT) * 128;
  int fr = lane & 15, fq = lane >> 4;
  int xorv = fr & 7;
  f32x4 acc[4][2] = {};
  int kIters = K / 64;
  int kp = lane >> 4;          // 0..3: k-pair rows {8w+2kp, 8w+2kp+1}
  int nlo = lane & 15;
  float4 bv[2][2];             // [half][k lo/hi]

  auto B_LOAD = [&](int it) {
    int k0 = it * 64;
#pragma unroll
    for (int h = 0; h < 2; ++h)
#pragma unroll
      for (int r = 0; r < 2; ++r)
        bv[h][r] = *(const float4*)(Bsrc + (size_t)(k0 + 8 * wave + 2 * kp + r) * N
                                    + n0 + (h * 16 + nlo) * 4);
  };
  auto B_WRITE = [&]() {
#pragma unroll
    for (int h = 0; h < 2; ++h) {
      const float* lo = (const float*)&bv[h][0];
      const float* hi = (const float*)&bv[h][1];
#pragma unroll
      for (int j = 0; j < 4; ++j) {
        int n = (h * 16 + nlo) * 4 + j;
        int swz = (n & 7) ^ ((n >> 3) & 7);
        unsigned pk = (unsigned)f2bf(lo[j]) | ((unsigned)f2bf(hi[j]) << 16);
        *(unsigned*)(BsB + n * 144 + ((wave ^ swz) << 4) + kp * 4) = pk;
      }
    }
  };
  auto A_STAGE = [&](int it, int buf) {
    int k0 = it * 64;
#pragma unroll
    for (int c = 0; c < 2; ++c) {
      int i = c * 512 + t;
      int row = i >> 3, c8 = i & 7;
      int sc = (c8 ^ (row & 7)) * 8;
      load_lds16(A + (size_t)(m0 + row) * K + k0 + sc, &As[buf][i * 8]);
    }
  };

  A_STAGE(0, 0);
  B_LOAD(0);
  int cur = 0;
  for (int it = 0; it < kIters; ++it) {
    __builtin_amdgcn_s_barrier();                       // prev MFMA done with As[cur^1], BsB
    if (it + 1 < kIters) {
      A_STAGE(it + 1, cur ^ 1);                         // 2 loads (newest)
      asm volatile("s_waitcnt vmcnt(2)" ::: "memory");  // drain A(it)2 + B(it)4
    } else {
      asm volatile("s_waitcnt vmcnt(0)" ::: "memory");
    }
    B_WRITE();                                          // BsB <- B(it)
    if (it + 1 < kIters) B_LOAD(it + 1);                // 4 loads in flight across MFMA
    asm volatile("s_waitcnt lgkmcnt(0)" ::: "memory");  // ds_writes drained (NOT vmcnt)
    __builtin_amdgcn_s_barrier();
    __builtin_amdgcn_s_setprio(1);
#pragma unroll
    for (int kk = 0; kk < 2; ++kk) {
      bf16x8 af[4], bfr[2];
#pragma unroll
      for (int mi = 0; mi < 4; ++mi)
        af[mi] = *(const bf16x8*)(&As[cur][(wr * 64 + mi * 16 + fr) * 64 + (((kk * 4 + fq) ^ xorv) << 3)]);
#pragma unroll
      for (int ni = 0; ni < 2; ++ni) {
        int n = wc * 32 + ni * 16 + fr;
        int swz = (n & 7) ^ ((n >> 3) & 7);
        bfr[ni] = *(const bf16x8*)(BsB + n * 144 + (((kk * 4 + fq) ^ swz) << 4));
      }
#pragma unroll
      for (int mi = 0; mi < 4; ++mi)
#pragma unroll
        for (int ni = 0; ni < 2; ++ni)
          acc[mi][ni] = __builtin_amdgcn_mfma_f32_16x16x32_bf16(af[mi], bfr[ni], acc[mi][ni], 0, 0, 0);
    }
    __builtin_amdgcn_s_setprio(0);
    cur ^= 1;
  }
#pragma unroll
  for (int mi = 0; mi < 4; ++mi)
#pragma unroll
    for (int ni = 0; ni < 2; ++ni)
#pragma unroll
      for (int j = 0; j < 4; ++j) {
        int r = m0 + wr * 64 + mi * 16 + fq * 4 + j;
        int cl = n0 + wc * 32 + ni * 16 + fr;
        C[(size_t)r * N + cl] = acc[mi][ni][j];
      }
}

// ---------------- Flash attention, bf16 MFMA (4 waves, QBLK=64; paired V staging) ----------------
__global__ __launch_bounds__(256) void attn_mfma_kernel(
    const unsigned short* __restrict__ qkvb, const int* __restrict__ amask,
    unsigned short* __restrict__ o) {
  __shared__ unsigned short Qs[64 * 72];
  __shared__ unsigned short Ks[64 * 72];
  __shared__ unsigned short Vt[64 * 72];   // [dh][key]
  __shared__ unsigned short Ps[4][16 * 72];
  __shared__ float msk[64];
  int bid = blockIdx.x;
  int qt = bid & 7, hh = (bid >> 3) & (H - 1), b = bid >> 7;
  int t = threadIdx.x;
  int lane = t & 63, w = t >> 6;
  int fr = lane & 15, fq = lane >> 4;
  size_t rowbase = (size_t)b * S;
  int q0 = qt * 64;
  const float scale = 0.125f;  // 1/sqrt(64)
#pragma unroll
  for (int c = 0; c < 2; ++c) {
    int i = c * 256 + t;
    int row = i >> 3, ch = i & 7;
    *(uint4*)(Qs + row * 72 + ch * 8) =
        *(const uint4*)(qkvb + (rowbase + q0 + row) * RS_QKV + hh * DH + ch * 8);
  }
  f32x4 oacc[4] = {};
  float m_old[4] = {-1e30f, -1e30f, -1e30f, -1e30f};
  float l[4] = {};
  int qbase = q0 + w * 16;
  for (int kt = 0; kt <= qt; ++kt) {
    int kk0 = kt * 64;
#pragma unroll
    for (int c = 0; c < 2; ++c) {
      int i = c * 256 + t;
      int row = i >> 3, ch = i & 7;
      uint4 kv = *(const uint4*)(qkvb + (rowbase + kk0 + row) * RS_QKV + D + hh * DH + ch * 8);
      *(uint4*)(Ks + row * 72 + ch * 8) = kv;
    }
#pragma unroll
    for (int c = 0; c < 2; ++c) {
      int idx = c * 256 + t;
      int rp = idx >> 4, dg = idx & 15;
      const unsigned short* vsrc = qkvb + (rowbase + kk0 + rp * 2) * RS_QKV + 2 * D + hh * DH + dg * 4;
      uint2 lo = *(const uint2*)vsrc;
      uint2 hi = *(const uint2*)(vsrc + RS_QKV);
      const unsigned short* ls = (const unsigned short*)&lo;
      const unsigned short* hs = (const unsigned short*)&hi;
#pragma unroll
      for (int q = 0; q < 4; ++q) {
        unsigned pk = (unsigned)ls[q] | ((unsigned)hs[q] << 16);
        *(unsigned*)(Vt + (dg * 4 + q) * 72 + rp * 2) = pk;
      }
    }
    if (t < 64) msk[t] = (amask[b * S + kk0 + t] > 0) ? 0.0f : -1e9f;
    __syncthreads();
    bf16x8 aq[2];
    aq[0] = *(const bf16x8*)(Qs + (w * 16 + fr) * 72 + fq * 8);
    aq[1] = *(const bf16x8*)(Qs + (w * 16 + fr) * 72 + 32 + fq * 8);
    f32x4 sacc[4];
#pragma unroll
    for (int ct = 0; ct < 4; ++ct) {
      bf16x8 bk0 = *(const bf16x8*)(Ks + (ct * 16 + fr) * 72 + fq * 8);
      bf16x8 bk1 = *(const bf16x8*)(Ks + (ct * 16 + fr) * 72 + 32 + fq * 8);
      f32x4 z = {};
      z = __builtin_amdgcn_mfma_f32_16x16x32_bf16(aq[0], bk0, z, 0, 0, 0);
      sacc[ct] = __builtin_amdgcn_mfma_f32_16x16x32_bf16(aq[1], bk1, z, 0, 0, 0);
    }
    float sv[4][4];
#pragma unroll
    for (int ct = 0; ct < 4; ++ct) {
      int kg = kk0 + ct * 16 + fr;
      float mk = msk[ct * 16 + fr];
#pragma unroll
      for (int j = 0; j < 4; ++j) {
        int qg = qbase + fq * 4 + j;
        float s = sacc[ct][j] * scale + mk;
        sv[ct][j] = (kg > qg) ? -1e9f : s;
      }
    }
    float mnew[4], f[4], rsum[4];
#pragma unroll
    for (int j = 0; j < 4; ++j) {
      float mt = fmaxf(fmaxf(sv[0][j], sv[1][j]), fmaxf(sv[2][j], sv[3][j]));
      for (int off = 1; off < 16; off <<= 1) mt = fmaxf(mt, __shfl_xor(mt, off));
      mnew[j] = fmaxf(m_old[j], mt);
      f[j] = __expf(m_old[j] - mnew[j]);
      float rs = 0.0f;
#pragma unroll
      for (int ct = 0; ct < 4; ++ct) {
        float e = __expf(sv[ct][j] - mnew[j]);
        sv[ct][j] = e;
        rs += e;
      }
      for (int off = 1; off < 16; off <<= 1) rs += __shfl_xor(rs, off);
      rsum[j] = rs;
      l[j] = l[j] * f[j] + rsum[j];
      m_old[j] = mnew[j];
#pragma unroll
      for (int dt = 0; dt < 4; ++dt) oacc[dt][j] *= f[j];
    }
#pragma unroll
    for (int ct = 0; ct < 4; ++ct)
#pragma unroll
      for (int j = 0; j < 4; ++j)
        Ps[w][(fq * 4 + j) * 72 + ct * 16 + fr] = f2bf(sv[ct][j]);
    __syncthreads();
    bf16x8 pa[2];
    pa[0] = *(const bf16x8*)(&Ps[w][fr * 72 + fq * 8]);
    pa[1] = *(const bf16x8*)(&Ps[w][fr * 72 + 32 + fq * 8]);
#pragma unroll
    for (int dt = 0; dt < 4; ++dt) {
      bf16x8 vb0 = *(const bf16x8*)(Vt + (dt * 16 + fr) * 72 + fq * 8);
      bf16x8 vb1 = *(const bf16x8*)(Vt + (dt * 16 + fr) * 72 + 32 + fq * 8);
      oacc[dt] = __builtin_amdgcn_mfma_f32_16x16x32_bf16(pa[0], vb0, oacc[dt], 0, 0, 0);
      oacc[dt] = __builtin_amdgcn_mfma_f32_16x16x32_bf16(pa[1], vb1, oacc[dt], 0, 0, 0);
    }
    __syncthreads();
  }
#pragma unroll
  for (int j = 0; j < 4; ++j) {
    float rinv = 1.0f / l[j];
    int qrow = qbase + fq * 4 + j;
#pragma unroll
    for (int dt = 0; dt < 4; ++dt)
      o[(rowbase + qrow) * D + hh * DH + dt * 16 + fr] = f2bf(oacc[dt][j] * rinv);
  }
}

extern "C" void kernel_launch(void* const* d_in, const int* in_sizes, int n_in,
                              void* d_out, int out_size, void* d_ws, size_t ws_size,
                              hipStream_t stream) {
  const int*   ids     = (const int*)d_in[0];
  const int*   amask   = (const int*)d_in[1];
  const float* emb     = (const float*)d_in[2];
  const float* ln1     = (const float*)d_in[3];
  const float* ln2     = (const float*)d_in[4];
  const float* wq = (const float*)d_in[5],  *aq = (const float*)d_in[6],  *bq = (const float*)d_in[7];
  const float* wk = (const float*)d_in[8],  *ak = (const float*)d_in[9],  *bk = (const float*)d_in[10];
  const float* wv = (const float*)d_in[11], *av = (const float*)d_in[12], *bv = (const float*)d_in[13];
  const float* wo = (const float*)d_in[14], *ao = (const float*)d_in[15], *bo = (const float*)d_in[16];
  const float* wg = (const float*)d_in[17], *ag = (const float*)d_in[18], *bg = (const float*)d_in[19];
  const float* wu = (const float*)d_in[20], *au = (const float*)d_in[21], *bu = (const float*)d_in[22];
  const float* wd = (const float*)d_in[23], *ad = (const float*)d_in[24], *bd = (const float*)d_in[25];
  const float* final_ln  = (const float*)d_in[26];
  const float* lm_head_w = (const float*)d_in[27];
  const float* value_w   = (const float*)d_in[28];
  const float* value_b   = (const float*)d_in[29];

  float* out    = (float*)d_out;
  float* logits = out;
  float* values = out + (size_t)BS * V;

  // ---- workspace ----
  float* Wf = (float*)d_ws;
  float* cosb = Wf; Wf += S * DH;
  float* sinb = Wf; Wf += S * DH;
  float* h    = Wf; Wf += (size_t)BS * D;
  unsigned short* Wb = (unsigned short*)Wf;
  unsigned short* x_bf  = Wb; Wb += (size_t)BS * D;
  unsigned short* t2e   = Wb; Wb += (size_t)BS * 64;
  unsigned short* qg    = Wb; Wb += (size_t)BS * F;      // shared: qkv_bf (3D) / gbf (F)
  unsigned short* gu_bf = Wb; Wb += (size_t)BS * RS_GU;  // obf aliases its head
  unsigned short* wqkvT = Wb; Wb += (size_t)L * 3 * D * D;
  unsigned short* woT   = Wb; Wb += (size_t)L * D * D;
  unsigned short* wguT  = Wb; Wb += (size_t)L * 2 * D * F;
  unsigned short* wdT   = Wb; Wb += (size_t)L * F * D;
  unsigned short* beQKV = Wb; Wb += (size_t)L * 3 * D * 64;
  unsigned short* beO   = Wb; Wb += (size_t)L * D * 64;
  unsigned short* beGU  = Wb; Wb += (size_t)L * 2 * F * 64;
  unsigned short* beD   = Wb; Wb += (size_t)L * D * 64;
  unsigned short* qkv_bf = qg;                 // [BS][3D]
  unsigned short* gbf    = qg;                 // [BS][F]
  unsigned short* obf    = gu_bf;              // [BS][D]

  // ---- merged weight transposes (layer weights only; lm consumed f32 in-GEMM) ----
  TDs td; int tblocks = 0; int di = 0;
  auto addT = [&](const float* s, unsigned short* dp, int K_, int N_) {
    td.d[di] = {s, dp, K_, N_, (K_ / 128) * (N_ / 64)};
    tblocks += td.d[di].nblk; ++di;
  };
  for (int l = 0; l < L; ++l) {
    size_t DD = (size_t)D * D, DF = (size_t)D * F;
    addT(wq + l * DD, wqkvT + (size_t)l * 3 * DD, D, D);
    addT(wk + l * DD, wqkvT + (size_t)l * 3 * DD + DD, D, D);
    addT(wv + l * DD, wqkvT + (size_t)l * 3 * DD + 2 * DD, D, D);
    addT(wo + l * DD, woT + l * DD, D, D);
    addT(wg + l * DF, wguT + (size_t)l * 2 * DF, D, F);
    addT(wu + l * DF, wguT + (size_t)l * 2 * DF + DF, D, F);
    addT(wd + l * DF, wdT + l * DF, F, D);
  }
  transpose_many_kernel<<<dim3(tblocks), 256, 0, stream>>>(td);

  // ---- merged bext (one dispatch) ----
  BDs bd2; int belems = 0; di = 0;
  auto addB = [&](const float* p0, const float* p1, const float* p2,
                  unsigned short* dst, int NA, int logW, int N_) {
    bd2.d[di] = {p0, p1, p2, dst, NA, logW, N_ * 64};
    belems += N_ * 64; ++di;
  };
  for (int l = 0; l < L; ++l) {
    size_t oRD = (size_t)l * R * D, oRF = (size_t)l * R * F;
    addB(bq + oRD, bk + oRD, bv + oRD, beQKV + (size_t)l * 3 * D * 64, 3, 10, 3 * D);
    addB(bo + oRD, nullptr, nullptr,   beO   + (size_t)l * D * 64,     1, 10, D);
    addB(bg + oRF, bu + oRF, nullptr,  beGU  + (size_t)l * 2 * F * 64, 2, 12, 2 * F);
    addB(bd + oRD, nullptr, nullptr,   beD   + (size_t)l * D * 64,     1, 10, D);
  }
  bext_many_kernel<<<dim3(belems / 256), 256, 0, stream>>>(bd2);

  rope_cache_kernel<<<dim3(S), dim3(32), 0, stream>>>(cosb, sinb);
  embed_kernel<<<dim3(BS), dim3(256), 0, stream>>>(ids, emb, h);

  for (int l = 0; l < L; ++l) {
    size_t DD = (size_t)D * D, DF = (size_t)D * F;
    size_t oDR = (size_t)l * D * R, oFR = (size_t)l * F * R;

    // ---- attention block ----
    { Ptr3 ap = {{aq + oDR, ak + oDR, av + oDR}};
      rms_lora_kernel<3><<<dim3(BS), 256, 0, stream>>>(h, ln1 + (size_t)l * D, ap, x_bf, t2e); }
    gemm_bf16_kernel<64, 128, false, true, 2><<<dim3(3 * D / 128, BS / 64), 256, 0, stream>>>(
        x_bf, wqkvT + (size_t)l * 3 * DD, qkv_bf, BS, 3 * D, D,
        t2e, beQKV + (size_t)l * 3 * D * 64, cosb, sinb);

    attn_mfma_kernel<<<dim3(B * H * (S / 64)), 256, 0, stream>>>(qkv_bf, amask, obf);

    lora_o_kernel<<<dim3(BS), 256, 0, stream>>>(obf, ao + oDR, t2e);
    gemm_bf16_kernel<64, 64, true, true, 0><<<dim3(D / 64, BS / 64), 256, 0, stream>>>(
        obf, woT + l * DD, h, BS, D, D, t2e, beO + (size_t)l * D * 64, nullptr, nullptr);

    // ---- MLP block ----
    { Ptr3 ap = {{ag + oDR, au + oDR, nullptr}};
      rms_lora_kernel<2><<<dim3(BS), 256, 0, stream>>>(h, ln2 + (size_t)l * D, ap, x_bf, t2e); }
    gemm_bf16_kernel<128, 128, false, true, 1><<<dim3(2 * F / 128, BS / 128), 256, 0, stream>>>(
        x_bf, wguT + (size_t)l * 2 * DF, gu_bf, BS, 2 * F, D,
        t2e, beGU + (size_t)l * 2 * F * 64, nullptr, nullptr);

    silu_lora_kernel<<<dim3(BS), 256, 0, stream>>>(gu_bf, ad + oFR, gbf, t2e);

    gemm_bf16_kernel<64, 64, true, true, 0><<<dim3(D / 64, BS / 64), 256, 0, stream>>>(
        gbf, wdT + l * DF, h, BS, D, F, t2e, beD + (size_t)l * D * 64, nullptr, nullptr);
  }

  // ---- final norm + fused value head + lm head (f32 B direct) ----
  rmsnorm_value_kernel<<<dim3(BS), 256, 0, stream>>>(h, final_ln, value_w, value_b, x_bf, values);
  gemm128f_kernel<<<dim3(V / 128, BS / 128), 512, 0, stream>>>(x_bf, lm_head_w, logits, BS, V, D);
}